// Round 18
// baseline (134.239 us; speedup 1.0000x reference)
//
#include <hip/hip_runtime.h>
#include <math.h>

#define Bq 2
#define Hq 128
#define Wq 256
#define Cq 64
#define HIDq 256
#define HWq (Hq * Wq)
#define NTOK (Bq * HWq)

#define TOKA 64
#define TOKB 64
#define TOKC 64
#define PIXD 32

typedef __attribute__((ext_vector_type(8))) short short8v;
typedef __attribute__((ext_vector_type(4))) float f32x4v;
typedef __attribute__((ext_vector_type(4))) unsigned short ushort4v;
typedef __attribute__((ext_vector_type(4))) unsigned int uint4v;

__device__ inline float gelu_exact(float x) {
    return 0.5f * x * (1.0f + erff(x * 0.70710678118654752440f));
}

__device__ inline unsigned short f2bf(float f) {
    unsigned int u = __float_as_uint(f);
    u += 0x7FFFu + ((u >> 16) & 1u);
    return (unsigned short)(u >> 16);
}

__device__ inline float bf2f(unsigned short u) {
    return __uint_as_float(((unsigned int)u) << 16);
}

// ============ Kernel P: pack weights -> bf16 transposed [col][k] in ws =======
__global__ __launch_bounds__(256) void kPrep(
    const float* __restrict__ W1, const float* __restrict__ W2,
    const float* __restrict__ Wv, const float* __restrict__ Woff, const float* __restrict__ Wa,
    unsigned short* __restrict__ w1t, unsigned short* __restrict__ w2t,
    unsigned short* __restrict__ wct)
{
    const int p = blockIdx.x * 256 + threadIdx.x;    // 80*256 = 20480
    if (p < 8192) {                                  // W1T: c 0..255, k2 0..31
        const int c = p >> 5, k2 = p & 31;
        const unsigned int pk = (unsigned int)f2bf(W1[(size_t)(2 * k2) * 256 + c])
                              | ((unsigned int)f2bf(W1[(size_t)(2 * k2 + 1) * 256 + c]) << 16);
        ((unsigned int*)w1t)[c * 32 + k2] = pk;
    } else if (p < 16384) {                          // W2T: c 0..63, k2 0..127
        const int q = p - 8192;
        const int c = q >> 7, k2 = q & 127;
        const unsigned int pk = (unsigned int)f2bf(W2[(size_t)(2 * k2) * 64 + c])
                              | ((unsigned int)f2bf(W2[(size_t)(2 * k2 + 1) * 64 + c]) << 16);
        ((unsigned int*)w2t)[c * 128 + k2] = pk;
    } else {                                         // WcT: c 0..127, k2 0..31
        const int q = p - 16384;
        const int c = q >> 5, k2 = q & 31;
        float w0 = 0.0f, w1 = 0.0f;
        if (c < 64)       { w0 = Wv[(size_t)(2 * k2) * 64 + c];          w1 = Wv[(size_t)(2 * k2 + 1) * 64 + c]; }
        else if (c < 100) { w0 = Woff[(size_t)(2 * k2) * 36 + (c - 64)]; w1 = Woff[(size_t)(2 * k2 + 1) * 36 + (c - 64)]; }
        else if (c < 118) { w0 = Wa[(size_t)(2 * k2) * 18 + (c - 100)];  w1 = Wa[(size_t)(2 * k2 + 1) * 18 + (c - 100)]; }
        const unsigned int pk = (unsigned int)f2bf(w0) | ((unsigned int)f2bf(w1) << 16);
        ((unsigned int*)wct)[c * 32 + k2] = pk;
    }
}

// ============ shared LN helper: thread=(tok,quarter) -> bf16 swizzled LDS ====
__device__ inline void ln_to_bf16_lds(
    const float* __restrict__ xsrc, const float* __restrict__ g, const float* __restrict__ be,
    int tok0, int t, unsigned short* __restrict__ hdst)
{
    const int tok = t >> 2, part = t & 3;
    const int chb = part * 16;
    const float* xp = xsrc + (size_t)(tok0 + tok) * 64 + chb;
    const float4 v0 = ((const float4*)xp)[0];
    const float4 v1 = ((const float4*)xp)[1];
    const float4 v2 = ((const float4*)xp)[2];
    const float4 v3 = ((const float4*)xp)[3];
    float s = ((v0.x + v0.y) + (v0.z + v0.w)) + ((v1.x + v1.y) + (v1.z + v1.w))
            + ((v2.x + v2.y) + (v2.z + v2.w)) + ((v3.x + v3.y) + (v3.z + v3.w));
    float s2 = 0.0f;
    s2 = fmaf(v0.x, v0.x, s2); s2 = fmaf(v0.y, v0.y, s2);
    s2 = fmaf(v0.z, v0.z, s2); s2 = fmaf(v0.w, v0.w, s2);
    s2 = fmaf(v1.x, v1.x, s2); s2 = fmaf(v1.y, v1.y, s2);
    s2 = fmaf(v1.z, v1.z, s2); s2 = fmaf(v1.w, v1.w, s2);
    s2 = fmaf(v2.x, v2.x, s2); s2 = fmaf(v2.y, v2.y, s2);
    s2 = fmaf(v2.z, v2.z, s2); s2 = fmaf(v2.w, v2.w, s2);
    s2 = fmaf(v3.x, v3.x, s2); s2 = fmaf(v3.y, v3.y, s2);
    s2 = fmaf(v3.z, v3.z, s2); s2 = fmaf(v3.w, v3.w, s2);
    s  += __shfl_xor(s, 1);  s2 += __shfl_xor(s2, 1);
    s  += __shfl_xor(s, 2);  s2 += __shfl_xor(s2, 2);
    const float m  = s * (1.0f / 64.0f);
    const float var = fmaf(-m, m, s2 * (1.0f / 64.0f));
    const float rs = rsqrtf(var + 1e-5f);
    const float nb = -m * rs;
    const float vv[16] = {v0.x,v0.y,v0.z,v0.w, v1.x,v1.y,v1.z,v1.w,
                          v2.x,v2.y,v2.z,v2.w, v3.x,v3.y,v3.z,v3.w};
    unsigned int pk[8];
    #pragma unroll
    for (int q = 0; q < 8; ++q) {
        const float hA = fmaf(fmaf(vv[2*q], rs, nb), g[chb + 2*q], be[chb + 2*q]);
        const float hB = fmaf(fmaf(vv[2*q+1], rs, nb), g[chb + 2*q+1], be[chb + 2*q+1]);
        pk[q] = (unsigned int)f2bf(hA) | ((unsigned int)f2bf(hB) << 16);
    }
    const unsigned int swz = ((unsigned int)(tok & 7)) << 3;
    unsigned int hi0 = ((unsigned int)(tok * 64 + chb)) ^ swz;
    unsigned int hi1 = ((unsigned int)(tok * 64 + chb + 8)) ^ swz;
    uint4 gA = {pk[0], pk[1], pk[2], pk[3]};
    uint4 gB = {pk[4], pk[5], pk[6], pk[7]};
    *(uint4*)&hdst[hi0] = gA;
    *(uint4*)&hdst[hi1] = gB;
}

// ============ Kernel A: LN1 + bf16 MFMA Wv -> v8 (fp8) =======================
// 256 threads (4 waves), 64 tokens/block.
__global__ __launch_bounds__(256) void kA(
    const float* __restrict__ x,
    const float* __restrict__ g1, const float* __restrict__ be1,
    const unsigned short* __restrict__ wct, const float* __restrict__ bv,
    unsigned char* __restrict__ v8)
{
    __shared__ unsigned short WvT[64 * 64];      // bf16 [col][k], swizzled (8 KB)
    __shared__ unsigned short hb[TOKA * 64];     // bf16 [tok][k], swizzled (8 KB)
    __shared__ unsigned char vtile[TOKA * 64];   // fp8 [tok][ch] (4 KB)
    const int t = threadIdx.x;
    const int tok0 = blockIdx.x * TOKA;
    const int b = tok0 >> 15;
    const int pix0 = tok0 & (HWq - 1);

    #pragma unroll
    for (int i = 0; i < 2; ++i) {
        const int q4 = t + i * 256;
        const uint4 d = ((const uint4*)wct)[q4];
        const int u0 = q4 * 4;
        const int c = u0 >> 5;
        const int udst = u0 ^ ((c & 7) << 2);
        *(uint4*)&((unsigned int*)WvT)[udst] = d;
    }
    ln_to_bf16_lds(x, g1, be1, tok0, t, hb);
    __syncthreads();

    const int lane = t & 63, wv = t >> 6;
    const int fr = lane & 15, kb = (lane >> 4) * 8;
    const int atok = wv * 16 + fr;
    f32x4v acc[4];
    #pragma unroll
    for (int nt = 0; nt < 4; ++nt) acc[nt] = (f32x4v){0.0f, 0.0f, 0.0f, 0.0f};
    #pragma unroll
    for (int ks = 0; ks < 2; ++ks) {
        const short8v a = *(const short8v*)&hb[(atok * 64 + ks * 32 + kb) ^ ((atok & 7) << 3)];
        #pragma unroll
        for (int nt = 0; nt < 4; ++nt) {
            const int col = nt * 16 + fr;
            const short8v bfr = *(const short8v*)&WvT[(col * 64 + ks * 32 + kb) ^ ((col & 7) << 3)];
            acc[nt] = __builtin_amdgcn_mfma_f32_16x16x32_bf16(a, bfr, acc[nt], 0, 0, 0);
        }
    }
    const int rbase = wv * 16 + (lane >> 4) * 4;
    #pragma unroll
    for (int nt = 0; nt < 4; ++nt) {
        const int col = nt * 16 + fr;
        const float bvv = bv[col];
        #pragma unroll
        for (int r = 0; r < 4; ++r) {
            const float val = acc[nt][r] + bvv;
            const int pk = __builtin_amdgcn_cvt_pk_fp8_f32(val, val, 0, false);
            vtile[(rbase + r) * 64 + col] = (unsigned char)(pk & 0xFF);
        }
    }
    __syncthreads();

    {
        const int tok = t >> 2, chunk = t & 3;
        const int n = chunk >> 1;
        const uint4 d = *(const uint4*)&vtile[tok * 64 + chunk * 16];
        *(uint4*)&v8[((size_t)(b * 2 + n) * HWq + pix0 + tok) * 32 + (chunk & 1) * 16] = d;
    }
}

// ============ Kernel B: LN1 + MFMA {Woff|Wa} + softmax + sample + Wo =========
// 256 threads (4 waves), 64 tokens/block. LDS 31744 B; atts overlaid on LG.
__global__ __launch_bounds__(256, 5) void kB(
    const float* __restrict__ x, const unsigned char* __restrict__ v8,
    const float* __restrict__ ref, const unsigned short* __restrict__ wct,
    const float* __restrict__ g1, const float* __restrict__ be1,
    const float* __restrict__ boff, const float* __restrict__ ba,
    const float* __restrict__ Wo, const float* __restrict__ bo,
    float* __restrict__ out)
{
    // float-index regions:
    // [0,4352)      sout[64][68]  (overlays wfa+hb, which die after MFMA)
    // [4352,6656)   locs[64][36]
    // [6656,7936)   LG[64][20]; softmax normalizes IN PLACE (atts = same region)
    __shared__ float ldsf[7936];
    unsigned short* lds16 = (unsigned short*)ldsf;   // wfa: 0..4095, hb: 4096..8191
    const int t = threadIdx.x;
    // XCD-chunked swizzle: 1024 blocks, 8 XCDs, 128 contiguous per XCD
    const int bid = (blockIdx.x & 7) * (NTOK / TOKB / 8) + (blockIdx.x >> 3);
    const int tok0 = bid * TOKB;
    const int b = tok0 >> 15;

    // ---- stage wct cols 64..127 -> lds16[0..4095] (swizzled)
    #pragma unroll
    for (int i = 0; i < 2; ++i) {
        const int q4 = t + i * 256;             // local uint4 idx, 512 total
        const uint4 d = ((const uint4*)wct)[q4 + 512];
        const int u0 = q4 * 4;
        const int c = u0 >> 5;
        const int udst = u0 ^ ((c & 7) << 2);
        *(uint4*)&((unsigned int*)lds16)[udst] = d;
    }
    ln_to_bf16_lds(x, g1, be1, tok0, t, lds16 + 4096);
    __syncthreads();

    // ---- MFMA: wave = M-tile (16 tok); 4 N-tiles (fused cols 64..127)
    const int lane = t & 63, wvid = t >> 6;
    {
        const int fr = lane & 15, kb = (lane >> 4) * 8;
        const int atok = wvid * 16 + fr;
        f32x4v acc[4];
        #pragma unroll
        for (int nt = 0; nt < 4; ++nt) acc[nt] = (f32x4v){0.0f, 0.0f, 0.0f, 0.0f};
        #pragma unroll
        for (int ks = 0; ks < 2; ++ks) {
            const short8v a = *(const short8v*)&lds16[4096 + ((atok * 64 + ks * 32 + kb) ^ ((atok & 7) << 3))];
            #pragma unroll
            for (int nt = 0; nt < 4; ++nt) {
                const int col = nt * 16 + fr;
                const short8v bfr = *(const short8v*)&lds16[(col * 64 + ks * 32 + kb) ^ ((col & 7) << 3)];
                acc[nt] = __builtin_amdgcn_mfma_f32_16x16x32_bf16(a, bfr, acc[nt], 0, 0, 0);
            }
        }
        const int rbase = wvid * 16 + (lane >> 4) * 4;
        #pragma unroll
        for (int nt = 0; nt < 4; ++nt) {
            const int col = nt * 16 + fr;
            if (col < 36) {
                const int rco = (col >= 18) ? col - 18 : col;
                const float bo_ = boff[col];
                #pragma unroll
                for (int r = 0; r < 4; ++r) {
                    const size_t tokg = (size_t)tok0 + rbase + r;
                    ldsf[4352 + (rbase + r) * 36 + col] = ref[tokg * 18 + rco] + acc[nt][r] + bo_;
                }
            } else if (col < 54) {
                const int lg = col - 36;
                const float bav = ba[lg];
                #pragma unroll
                for (int r = 0; r < 4; ++r) ldsf[6656 + (rbase + r) * 20 + lg] = acc[nt][r] + bav;
            }
        }
    }
    __syncthreads();

    // ---- softmax per (token, head): normalize LG in place
    if (t < TOKB * 2) {
        const int tk = t >> 1, head = t & 1;
        float mx = -1e30f;
        #pragma unroll
        for (int k = 0; k < 9; ++k) mx = fmaxf(mx, ldsf[6656 + tk * 20 + head * 9 + k]);
        float e[9], s = 0.0f;
        #pragma unroll
        for (int k = 0; k < 9; ++k) { e[k] = expf(ldsf[6656 + tk * 20 + head * 9 + k] - mx); s += e[k]; }
        const float inv = 1.0f / s;
        #pragma unroll
        for (int k = 0; k < 9; ++k) ldsf[6656 + tk * 20 + head * 9 + k] = e[k] * inv;
    }
    __syncthreads();

    // ---- sampling: lane = half(bit0)|head(bit1)|tok(bits2-5); 16 ch/lane
    {
        const int half = lane & 1;
        const int n = (lane >> 1) & 1;
        const int tkl = wvid * 16 + (lane >> 2);
        const unsigned char* __restrict__ vimg =
            v8 + (size_t)(b * 2 + n) * HWq * 32 + half * 16;

        float a[16];
        #pragma unroll
        for (int j = 0; j < 16; ++j) a[j] = 0.0f;

        #pragma unroll
        for (int k = 0; k < 9; ++k) {
            const float2 g = *(const float2*)&ldsf[4352 + tkl * 36 + n * 18 + 2 * k];
            const float at = ldsf[6656 + tkl * 20 + n * 9 + k];
            const float ix = fmaf(g.x, 128.0f, 127.5f);
            const float iy = fmaf(g.y, 64.0f, 63.5f);
            const float x0f = floorf(ix), y0f = floorf(iy);
            const float wx1 = ix - x0f, wy1 = iy - y0f;
            const float wx0 = 1.0f - wx1, wy0 = 1.0f - wy1;
            const int x0 = (int)x0f, y0 = (int)y0f;
            const int x1i = x0 + 1, y1i = y0 + 1;
            const int x0c = min(max(x0, 0), Wq - 1), y0c = min(max(y0, 0), Hq - 1);
            const int x1c = min(max(x1i, 0), Wq - 1), y1c = min(max(y1i, 0), Hq - 1);
            const bool vx0 = (x0 >= 0) & (x0 <= Wq - 1);
            const bool vy0 = (y0 >= 0) & (y0 <= Hq - 1);
            const bool vx1 = (x1i >= 0) & (x1i <= Wq - 1);
            const bool vy1 = (y1i >= 0) & (y1i <= Hq - 1);
            const float ax0 = at * wx0, ax1 = at * wx1;
            const float w00 = (vx0 && vy0) ? ax0 * wy0 : 0.0f;
            const float w10 = (vx1 && vy0) ? ax1 * wy0 : 0.0f;
            const float w01 = (vx0 && vy1) ? ax0 * wy1 : 0.0f;
            const float w11 = (vx1 && vy1) ? ax1 * wy1 : 0.0f;
            const int p00 = (((y0c << 8) + x0c) << 5), p10 = (((y0c << 8) + x1c) << 5);
            const int p01 = (((y1c << 8) + x0c) << 5), p11 = (((y1c << 8) + x1c) << 5);
            const uint4v q00 = *(const uint4v*)(vimg + p00);
            const uint4v q10 = *(const uint4v*)(vimg + p10);
            const uint4v q01 = *(const uint4v*)(vimg + p01);
            const uint4v q11 = *(const uint4v*)(vimg + p11);
            #pragma unroll
            for (int j = 0; j < 4; ++j) {
                {
                    auto lo = __builtin_amdgcn_cvt_pk_f32_fp8(q00[j], false);
                    auto hi = __builtin_amdgcn_cvt_pk_f32_fp8(q00[j], true);
                    a[4*j+0] = fmaf(w00, lo[0], a[4*j+0]); a[4*j+1] = fmaf(w00, lo[1], a[4*j+1]);
                    a[4*j+2] = fmaf(w00, hi[0], a[4*j+2]); a[4*j+3] = fmaf(w00, hi[1], a[4*j+3]);
                }
                {
                    auto lo = __builtin_amdgcn_cvt_pk_f32_fp8(q10[j], false);
                    auto hi = __builtin_amdgcn_cvt_pk_f32_fp8(q10[j], true);
                    a[4*j+0] = fmaf(w10, lo[0], a[4*j+0]); a[4*j+1] = fmaf(w10, lo[1], a[4*j+1]);
                    a[4*j+2] = fmaf(w10, hi[0], a[4*j+2]); a[4*j+3] = fmaf(w10, hi[1], a[4*j+3]);
                }
                {
                    auto lo = __builtin_amdgcn_cvt_pk_f32_fp8(q01[j], false);
                    auto hi = __builtin_amdgcn_cvt_pk_f32_fp8(q01[j], true);
                    a[4*j+0] = fmaf(w01, lo[0], a[4*j+0]); a[4*j+1] = fmaf(w01, lo[1], a[4*j+1]);
                    a[4*j+2] = fmaf(w01, hi[0], a[4*j+2]); a[4*j+3] = fmaf(w01, hi[1], a[4*j+3]);
                }
                {
                    auto lo = __builtin_amdgcn_cvt_pk_f32_fp8(q11[j], false);
                    auto hi = __builtin_amdgcn_cvt_pk_f32_fp8(q11[j], true);
                    a[4*j+0] = fmaf(w11, lo[0], a[4*j+0]); a[4*j+1] = fmaf(w11, lo[1], a[4*j+1]);
                    a[4*j+2] = fmaf(w11, hi[0], a[4*j+2]); a[4*j+3] = fmaf(w11, hi[1], a[4*j+3]);
                }
            }
        }
        const int ch0 = n * 32 + half * 16;
        float4 o0 = {a[0], a[1], a[2], a[3]};
        float4 o1 = {a[4], a[5], a[6], a[7]};
        float4 o2 = {a[8], a[9], a[10], a[11]};
        float4 o3 = {a[12], a[13], a[14], a[15]};
        *(float4*)&ldsf[tkl * 68 + ch0 + 0]  = o0;
        *(float4*)&ldsf[tkl * 68 + ch0 + 4]  = o1;
        *(float4*)&ldsf[tkl * 68 + ch0 + 8]  = o2;
        *(float4*)&ldsf[tkl * 68 + ch0 + 12] = o3;
    }
    __syncthreads();

    // ---- Wo GEMM: thread -> 2 tokens (t>>3), 8 cols ((t&7)*8); Wo via L1
    const int tg = t >> 3, cg8 = t & 7;
    const int tb = tg * 2, cb = cg8 * 8;
    float accw[2][8];
    #pragma unroll
    for (int i = 0; i < 2; ++i)
        #pragma unroll
        for (int q = 0; q < 8; ++q) accw[i][q] = 0.0f;

    for (int j = 0; j < 64; j += 4) {
        const float4 h0 = *(const float4*)&ldsf[(tb + 0) * 68 + j];
        const float4 h1 = *(const float4*)&ldsf[(tb + 1) * 68 + j];
        const float hv[2][4] = {{h0.x,h0.y,h0.z,h0.w},{h1.x,h1.y,h1.z,h1.w}};
        #pragma unroll
        for (int jj = 0; jj < 4; ++jj) {
            const float4 wA = *(const float4*)&Wo[(size_t)(j + jj) * 64 + cb];
            const float4 wB = *(const float4*)&Wo[(size_t)(j + jj) * 64 + cb + 4];
            const float wv8[8] = {wA.x,wA.y,wA.z,wA.w,wB.x,wB.y,wB.z,wB.w};
            #pragma unroll
            for (int i = 0; i < 2; ++i)
                #pragma unroll
                for (int q = 0; q < 8; ++q)
                    accw[i][q] = fmaf(hv[i][jj], wv8[q], accw[i][q]);
        }
    }
    const float4 boA = *(const float4*)&bo[cb];
    const float4 boB = *(const float4*)&bo[cb + 4];
    #pragma unroll
    for (int i = 0; i < 2; ++i) {
        const size_t tokg = (size_t)tok0 + tb + i;
        const float4 rA = *(const float4*)&x[tokg * 64 + cb];
        const float4 rB = *(const float4*)&x[tokg * 64 + cb + 4];
        float4 oA = {accw[i][0]+boA.x+rA.x, accw[i][1]+boA.y+rA.y,
                     accw[i][2]+boA.z+rA.z, accw[i][3]+boA.w+rA.w};
        float4 oB = {accw[i][4]+boB.x+rB.x, accw[i][5]+boB.y+rB.y,
                     accw[i][6]+boB.z+rB.z, accw[i][7]+boB.w+rB.w};
        *(float4*)&out[tokg * 64 + cb] = oA;
        *(float4*)&out[tokg * 64 + cb + 4] = oB;
    }
}

// ============ Kernel C: LN2 + bf16 MFMA W1 + GELU -> y (fp8) =================
// 512 threads (8 waves), 64 tokens/block.
__global__ __launch_bounds__(512) void kC(
    const float* __restrict__ x1, const float* __restrict__ g2, const float* __restrict__ be2,
    const unsigned short* __restrict__ w1t, const float* __restrict__ c1,
    unsigned char* __restrict__ y8)
{
    __shared__ unsigned short W1T[256 * 64];    // bf16 [col][k], swizzled (32 KB)
    __shared__ unsigned short hb2[TOKC * 64];   // bf16 [tok][k], swizzled (8 KB)
    __shared__ unsigned char ytile8[TOKC * 256];// fp8 [tok][col], swizzled (16 KB)
    const int t = threadIdx.x;
    const int tok0 = blockIdx.x * TOKC;

    #pragma unroll
    for (int i = 0; i < 4; ++i) {
        const int q4 = t + i * 512;
        const uint4 d = ((const uint4*)w1t)[q4];
        const int u0 = q4 * 4;
        const int c = u0 >> 5;
        const int udst = u0 ^ ((c & 7) << 2);
        *(uint4*)&((unsigned int*)W1T)[udst] = d;
    }
    if (t < TOKC * 4) ln_to_bf16_lds(x1, g2, be2, tok0, t, hb2);
    __syncthreads();

    const int lane = t & 63, wv = t >> 6;
    const int mtile = wv & 3, nquad = wv >> 2;
    const int fr = lane & 15, kb = (lane >> 4) * 8;
    const int atok = mtile * 16 + fr;
    f32x4v acc[8];
    #pragma unroll
    for (int nt = 0; nt < 8; ++nt) acc[nt] = (f32x4v){0.0f, 0.0f, 0.0f, 0.0f};

    #pragma unroll
    for (int ks = 0; ks < 2; ++ks) {
        const short8v a = *(const short8v*)&hb2[(atok * 64 + ks * 32 + kb) ^ ((atok & 7) << 3)];
        #pragma unroll
        for (int nt = 0; nt < 8; ++nt) {
            const int col = nquad * 128 + nt * 16 + fr;
            const short8v bfr = *(const short8v*)&W1T[(col * 64 + ks * 32 + kb) ^ ((col & 7) << 3)];
            acc[nt] = __builtin_amdgcn_mfma_f32_16x16x32_bf16(a, bfr, acc[nt], 0, 0, 0);
        }
    }

    #pragma unroll
    for (int nt = 0; nt < 8; ++nt) {
        const int col = nquad * 128 + nt * 16 + fr;
        const float c1v = c1[col];
        #pragma unroll
        for (int r = 0; r < 4; ++r) {
            const int tok = mtile * 16 + (lane >> 4) * 4 + r;
            const float val = gelu_exact(acc[nt][r] + c1v);
            const int pk = __builtin_amdgcn_cvt_pk_fp8_f32(val, val, 0, false);
            ytile8[((unsigned)(tok * 256 + col)) ^ (((unsigned)(tok & 7)) << 4)] = (unsigned char)(pk & 0xFF);
        }
    }
    __syncthreads();

    {
        const int row = t >> 3, cb = (t & 7) * 32;
        const unsigned int swz = ((unsigned int)(row & 7)) << 4;
        unsigned char* dst = y8 + (size_t)(tok0 + row) * 256 + cb;
        #pragma unroll
        for (int j = 0; j < 2; ++j) {
            const unsigned int bidx = ((unsigned int)(row * 256 + cb + j * 16)) ^ swz;
            *(uint4*)(dst + j * 16) = *(const uint4*)&ytile8[bidx];
        }
    }
}

// ============ Kernel D: depthwise 3x3 (fp8 y) + GELU + MFMA W2 ===============
// 256 threads. LDS: zsb2 only (16 KB) -> high occupancy.
__global__ __launch_bounds__(256) void kD(
    const unsigned char* __restrict__ y8, const float* __restrict__ Wdw, const float* __restrict__ bdw,
    const unsigned short* __restrict__ w2t, const float* __restrict__ c2,
    float* __restrict__ out)
{
    __shared__ unsigned short zsb2[PIXD * 256]; // bf16 [pix][k], swizzled (16 KB)
    const int t = threadIdx.x;
    const int bid = (blockIdx.x & 7) * 256 + (blockIdx.x >> 3);
    const int b = bid >> 10;
    const int rem = bid & 1023;
    const int hh = rem >> 3;
    const int ww0 = (rem & 7) * PIXD;

    {
        const int lane = t & 63, sub = t >> 6;
        const int c4 = lane * 4;
        const int px0 = ww0 + sub * 8;
        const unsigned char* __restrict__ yb = y8 + (size_t)b * HWq * 256;
        const bool r0ok = (hh > 0), r2ok = (hh < Hq - 1);
        const int y0r = (hh - 1) << 8, y1r = hh << 8, y2r = (hh + 1) << 8;

        float um1[3][4], uz0[3][4], up1[3][4];
        #define LOADCOL(dst, xx) do {                                              \
            const unsigned int u0v = r0ok ? *(const unsigned int*)&yb[((size_t)(y0r + (xx)) << 8) + c4] : 0u; \
            const unsigned int u1v =        *(const unsigned int*)&yb[((size_t)(y1r + (xx)) << 8) + c4]; \
            const unsigned int u2v = r2ok ? *(const unsigned int*)&yb[((size_t)(y2r + (xx)) << 8) + c4] : 0u; \
            { auto lo = __builtin_amdgcn_cvt_pk_f32_fp8(u0v, false);               \
              auto hi = __builtin_amdgcn_cvt_pk_f32_fp8(u0v, true);                \
              dst[0][0] = lo[0]; dst[0][1] = lo[1]; dst[0][2] = hi[0]; dst[0][3] = hi[1]; } \
            { auto lo = __builtin_amdgcn_cvt_pk_f32_fp8(u1v, false);               \
              auto hi = __builtin_amdgcn_cvt_pk_f32_fp8(u1v, true);                \
              dst[1][0] = lo[0]; dst[1][1] = lo[1]; dst[1][2] = hi[0]; dst[1][3] = hi[1]; } \
            { auto lo = __builtin_amdgcn_cvt_pk_f32_fp8(u2v, false);               \
              auto hi = __builtin_amdgcn_cvt_pk_f32_fp8(u2v, true);                \
              dst[2][0] = lo[0]; dst[2][1] = lo[1]; dst[2][2] = hi[0]; dst[2][3] = hi[1]; } \
        } while (0)

        float wd[9][4], bdv[4];
        #pragma unroll
        for (int j = 0; j < 4; ++j) {
            bdv[j] = bdw[c4 + j];
            #pragma unroll
            for (int q = 0; q < 9; ++q) wd[q][j] = Wdw[(c4 + j) * 9 + q];
        }

        LOADCOL(um1, (px0 - 1) & 255);
        LOADCOL(uz0, px0);
        #pragma unroll
        for (int p = 0; p < 8; ++p) {
            LOADCOL(up1, (px0 + p + 1) & 255);
            unsigned short zq[4];
            #pragma unroll
            for (int j = 0; j < 4; ++j) {
                float a = bdv[j];
                #pragma unroll
                for (int ky = 0; ky < 3; ++ky) {
                    a = fmaf(wd[ky * 3 + 0][j], um1[ky][j], a);
                    a = fmaf(wd[ky * 3 + 1][j], uz0[ky][j], a);
                    a = fmaf(wd[ky * 3 + 2][j], up1[ky][j], a);
                }
                zq[j] = f2bf(gelu_exact(a));
            }
            const int pix = sub * 8 + p;
            ushort4v zv = {zq[0], zq[1], zq[2], zq[3]};
            *(ushort4v*)&zsb2[((unsigned)(pix * 256 + c4)) ^ (((unsigned)(pix & 7)) << 3)] = zv;
            #pragma unroll
            for (int ky = 0; ky < 3; ++ky)
                #pragma unroll
                for (int j = 0; j < 4; ++j) { um1[ky][j] = uz0[ky][j]; uz0[ky][j] = up1[ky][j]; }
        }
        #undef LOADCOL
    }
    __syncthreads();

    const int lane = t & 63, wv = t >> 6;
    const int fr = lane & 15;
    const int kb = (lane >> 4) * 8;
    const int col = wv * 16 + fr;
    f32x4v acc0 = {0.0f, 0.0f, 0.0f, 0.0f};
    f32x4v acc1 = {0.0f, 0.0f, 0.0f, 0.0f};
    #pragma unroll
    for (int kk = 0; kk < 8; ++kk) {
        const int ka = kk * 32 + kb;
        const short8v bfr = *(const short8v*)&w2t[(size_t)col * 256 + ka];
        const short8v a0 = *(const short8v*)&zsb2[(fr * 256 + ka) ^ ((fr & 7) << 3)];
        const short8v a1 = *(const short8v*)&zsb2[((fr + 16) * 256 + ka) ^ ((fr & 7) << 3)];
        acc0 = __builtin_amdgcn_mfma_f32_16x16x32_bf16(a0, bfr, acc0, 0, 0, 0);
        acc1 = __builtin_amdgcn_mfma_f32_16x16x32_bf16(a1, bfr, acc1, 0, 0, 0);
    }
    const float c2v = c2[col];
    #pragma unroll
    for (int r = 0; r < 4; ++r) {
        const int prow = (lane >> 4) * 4 + r;
        const size_t tok0g = (size_t)b * HWq + ((size_t)hh << 8) + ww0;
        out[(tok0g + prow) * 64 + col] += acc0[r] + c2v;
        out[(tok0g + 16 + prow) * 64 + col] += acc1[r] + c2v;
    }
}

extern "C" void kernel_launch(void* const* d_in, const int* in_sizes, int n_in,
                              void* d_out, int out_size, void* d_ws, size_t ws_size,
                              hipStream_t stream) {
    const float* x    = (const float*)d_in[0];
    const float* ref  = (const float*)d_in[1];
    const float* g1   = (const float*)d_in[2];
    const float* be1  = (const float*)d_in[3];
    const float* g2   = (const float*)d_in[4];
    const float* be2  = (const float*)d_in[5];
    const float* Woff = (const float*)d_in[6];
    const float* boff = (const float*)d_in[7];
    const float* Wa   = (const float*)d_in[8];
    const float* ba   = (const float*)d_in[9];
    const float* Wv   = (const float*)d_in[10];
    const float* bv   = (const float*)d_in[11];
    const float* Wo   = (const float*)d_in[12];
    const float* bo   = (const float*)d_in[13];
    const float* W1   = (const float*)d_in[14];
    const float* c1   = (const float*)d_in[15];
    const float* Wdw  = (const float*)d_in[16];
    const float* bdw  = (const float*)d_in[17];
    const float* W2   = (const float*)d_in[18];
    const float* c2   = (const float*)d_in[19];

    float* out = (float*)d_out;
    unsigned char* wsb = (unsigned char*)d_ws;
    unsigned char* v8 = wsb;                                        // 4 MB
    unsigned char* y8 = v8 + (size_t)Bq * 2 * HWq * 32;             // 16.8 MB
    unsigned short* w1t = (unsigned short*)(y8 + (size_t)NTOK * 256);
    unsigned short* w2t = w1t + 256 * 64;
    unsigned short* wct = w2t + 64 * 256;

    hipLaunchKernelGGL(kPrep, dim3(80), dim3(256), 0, stream,
                       W1, W2, Wv, Woff, Wa, w1t, w2t, wct);
    hipLaunchKernelGGL(kA, dim3(NTOK / TOKA), dim3(256), 0, stream,
                       x, g1, be1, wct, bv, v8);
    hipLaunchKernelGGL(kB, dim3(NTOK / TOKB), dim3(256), 0, stream,
                       x, v8, ref, wct, g1, be1, boff, ba, Wo, bo, out);
    hipLaunchKernelGGL(kC, dim3(NTOK / TOKC), dim3(512), 0, stream,
                       out, g2, be2, w1t, c1, y8);
    hipLaunchKernelGGL(kD, dim3(Bq * Hq * (Wq / PIXD)), dim3(256), 0, stream,
                       y8, Wdw, bdw, w2t, c2, out);
}

// Round 19
// 99.568 us; speedup vs baseline: 1.3482x; 1.3482x over previous
//
#include <hip/hip_runtime.h>
#include <math.h>

#define Bq 2
#define Hq 128
#define Wq 256
#define Cq 64
#define HIDq 256
#define HWq (Hq * Wq)
#define NTOK (Bq * HWq)

#define TOKA 64
#define TOKB 64
#define TOKC 64
#define PIXD 32

typedef __attribute__((ext_vector_type(8))) short short8v;
typedef __attribute__((ext_vector_type(4))) float f32x4v;
typedef __attribute__((ext_vector_type(4))) unsigned short ushort4v;
typedef __attribute__((ext_vector_type(4))) unsigned int uint4v;

__device__ inline float gelu_exact(float x) {
    return 0.5f * x * (1.0f + erff(x * 0.70710678118654752440f));
}

__device__ inline unsigned short f2bf(float f) {
    unsigned int u = __float_as_uint(f);
    u += 0x7FFFu + ((u >> 16) & 1u);
    return (unsigned short)(u >> 16);
}

__device__ inline float bf2f(unsigned short u) {
    return __uint_as_float(((unsigned int)u) << 16);
}

// ============ Kernel P: pack weights -> bf16 transposed [col][k] in ws =======
__global__ __launch_bounds__(256) void kPrep(
    const float* __restrict__ W1, const float* __restrict__ W2,
    const float* __restrict__ Wv, const float* __restrict__ Woff, const float* __restrict__ Wa,
    unsigned short* __restrict__ w1t, unsigned short* __restrict__ w2t,
    unsigned short* __restrict__ wct)
{
    const int p = blockIdx.x * 256 + threadIdx.x;    // 80*256 = 20480
    if (p < 8192) {                                  // W1T: c 0..255, k2 0..31
        const int c = p >> 5, k2 = p & 31;
        const unsigned int pk = (unsigned int)f2bf(W1[(size_t)(2 * k2) * 256 + c])
                              | ((unsigned int)f2bf(W1[(size_t)(2 * k2 + 1) * 256 + c]) << 16);
        ((unsigned int*)w1t)[c * 32 + k2] = pk;
    } else if (p < 16384) {                          // W2T: c 0..63, k2 0..127
        const int q = p - 8192;
        const int c = q >> 7, k2 = q & 127;
        const unsigned int pk = (unsigned int)f2bf(W2[(size_t)(2 * k2) * 64 + c])
                              | ((unsigned int)f2bf(W2[(size_t)(2 * k2 + 1) * 64 + c]) << 16);
        ((unsigned int*)w2t)[c * 128 + k2] = pk;
    } else {                                         // WcT: c 0..127, k2 0..31
        const int q = p - 16384;
        const int c = q >> 5, k2 = q & 31;
        float w0 = 0.0f, w1 = 0.0f;
        if (c < 64)       { w0 = Wv[(size_t)(2 * k2) * 64 + c];          w1 = Wv[(size_t)(2 * k2 + 1) * 64 + c]; }
        else if (c < 100) { w0 = Woff[(size_t)(2 * k2) * 36 + (c - 64)]; w1 = Woff[(size_t)(2 * k2 + 1) * 36 + (c - 64)]; }
        else if (c < 118) { w0 = Wa[(size_t)(2 * k2) * 18 + (c - 100)];  w1 = Wa[(size_t)(2 * k2 + 1) * 18 + (c - 100)]; }
        const unsigned int pk = (unsigned int)f2bf(w0) | ((unsigned int)f2bf(w1) << 16);
        ((unsigned int*)wct)[c * 32 + k2] = pk;
    }
}

// ============ shared LN helper: thread=(tok,quarter) -> bf16 swizzled LDS ====
__device__ inline void ln_to_bf16_lds(
    const float* __restrict__ xsrc, const float* __restrict__ g, const float* __restrict__ be,
    int tok0, int t, unsigned short* __restrict__ hdst)
{
    const int tok = t >> 2, part = t & 3;
    const int chb = part * 16;
    const float* xp = xsrc + (size_t)(tok0 + tok) * 64 + chb;
    const float4 v0 = ((const float4*)xp)[0];
    const float4 v1 = ((const float4*)xp)[1];
    const float4 v2 = ((const float4*)xp)[2];
    const float4 v3 = ((const float4*)xp)[3];
    float s = ((v0.x + v0.y) + (v0.z + v0.w)) + ((v1.x + v1.y) + (v1.z + v1.w))
            + ((v2.x + v2.y) + (v2.z + v2.w)) + ((v3.x + v3.y) + (v3.z + v3.w));
    float s2 = 0.0f;
    s2 = fmaf(v0.x, v0.x, s2); s2 = fmaf(v0.y, v0.y, s2);
    s2 = fmaf(v0.z, v0.z, s2); s2 = fmaf(v0.w, v0.w, s2);
    s2 = fmaf(v1.x, v1.x, s2); s2 = fmaf(v1.y, v1.y, s2);
    s2 = fmaf(v1.z, v1.z, s2); s2 = fmaf(v1.w, v1.w, s2);
    s2 = fmaf(v2.x, v2.x, s2); s2 = fmaf(v2.y, v2.y, s2);
    s2 = fmaf(v2.z, v2.z, s2); s2 = fmaf(v2.w, v2.w, s2);
    s2 = fmaf(v3.x, v3.x, s2); s2 = fmaf(v3.y, v3.y, s2);
    s2 = fmaf(v3.z, v3.z, s2); s2 = fmaf(v3.w, v3.w, s2);
    s  += __shfl_xor(s, 1);  s2 += __shfl_xor(s2, 1);
    s  += __shfl_xor(s, 2);  s2 += __shfl_xor(s2, 2);
    const float m  = s * (1.0f / 64.0f);
    const float var = fmaf(-m, m, s2 * (1.0f / 64.0f));
    const float rs = rsqrtf(var + 1e-5f);
    const float nb = -m * rs;
    const float vv[16] = {v0.x,v0.y,v0.z,v0.w, v1.x,v1.y,v1.z,v1.w,
                          v2.x,v2.y,v2.z,v2.w, v3.x,v3.y,v3.z,v3.w};
    unsigned int pk[8];
    #pragma unroll
    for (int q = 0; q < 8; ++q) {
        const float hA = fmaf(fmaf(vv[2*q], rs, nb), g[chb + 2*q], be[chb + 2*q]);
        const float hB = fmaf(fmaf(vv[2*q+1], rs, nb), g[chb + 2*q+1], be[chb + 2*q+1]);
        pk[q] = (unsigned int)f2bf(hA) | ((unsigned int)f2bf(hB) << 16);
    }
    const unsigned int swz = ((unsigned int)(tok & 7)) << 3;
    unsigned int hi0 = ((unsigned int)(tok * 64 + chb)) ^ swz;
    unsigned int hi1 = ((unsigned int)(tok * 64 + chb + 8)) ^ swz;
    uint4 gA = {pk[0], pk[1], pk[2], pk[3]};
    uint4 gB = {pk[4], pk[5], pk[6], pk[7]};
    *(uint4*)&hdst[hi0] = gA;
    *(uint4*)&hdst[hi1] = gB;
}

// ============ Kernel A: LN1 + bf16 MFMA Wv -> v8 (fp8) =======================
// 256 threads (4 waves), 64 tokens/block.
__global__ __launch_bounds__(256) void kA(
    const float* __restrict__ x,
    const float* __restrict__ g1, const float* __restrict__ be1,
    const unsigned short* __restrict__ wct, const float* __restrict__ bv,
    unsigned char* __restrict__ v8)
{
    __shared__ unsigned short WvT[64 * 64];      // bf16 [col][k], swizzled (8 KB)
    __shared__ unsigned short hb[TOKA * 64];     // bf16 [tok][k], swizzled (8 KB)
    __shared__ unsigned char vtile[TOKA * 64];   // fp8 [tok][ch] (4 KB)
    const int t = threadIdx.x;
    const int tok0 = blockIdx.x * TOKA;
    const int b = tok0 >> 15;
    const int pix0 = tok0 & (HWq - 1);

    #pragma unroll
    for (int i = 0; i < 2; ++i) {
        const int q4 = t + i * 256;
        const uint4 d = ((const uint4*)wct)[q4];
        const int u0 = q4 * 4;
        const int c = u0 >> 5;
        const int udst = u0 ^ ((c & 7) << 2);
        *(uint4*)&((unsigned int*)WvT)[udst] = d;
    }
    ln_to_bf16_lds(x, g1, be1, tok0, t, hb);
    __syncthreads();

    const int lane = t & 63, wv = t >> 6;
    const int fr = lane & 15, kb = (lane >> 4) * 8;
    const int atok = wv * 16 + fr;
    f32x4v acc[4];
    #pragma unroll
    for (int nt = 0; nt < 4; ++nt) acc[nt] = (f32x4v){0.0f, 0.0f, 0.0f, 0.0f};
    #pragma unroll
    for (int ks = 0; ks < 2; ++ks) {
        const short8v a = *(const short8v*)&hb[(atok * 64 + ks * 32 + kb) ^ ((atok & 7) << 3)];
        #pragma unroll
        for (int nt = 0; nt < 4; ++nt) {
            const int col = nt * 16 + fr;
            const short8v bfr = *(const short8v*)&WvT[(col * 64 + ks * 32 + kb) ^ ((col & 7) << 3)];
            acc[nt] = __builtin_amdgcn_mfma_f32_16x16x32_bf16(a, bfr, acc[nt], 0, 0, 0);
        }
    }
    const int rbase = wv * 16 + (lane >> 4) * 4;
    #pragma unroll
    for (int nt = 0; nt < 4; ++nt) {
        const int col = nt * 16 + fr;
        const float bvv = bv[col];
        #pragma unroll
        for (int r = 0; r < 4; ++r) {
            const float val = acc[nt][r] + bvv;
            const int pk = __builtin_amdgcn_cvt_pk_fp8_f32(val, val, 0, false);
            vtile[(rbase + r) * 64 + col] = (unsigned char)(pk & 0xFF);
        }
    }
    __syncthreads();

    {
        const int tok = t >> 2, chunk = t & 3;
        const int n = chunk >> 1;
        const uint4 d = *(const uint4*)&vtile[tok * 64 + chunk * 16];
        *(uint4*)&v8[((size_t)(b * 2 + n) * HWq + pix0 + tok) * 32 + (chunk & 1) * 16] = d;
    }
}

// ============ Kernel B: LN1 + MFMA {Woff|Wa} + softmax + sample + Wo =========
// 256 threads (4 waves), 64 tokens/block. LDS 31744 B; atts overlaid on LG.
__global__ __launch_bounds__(256) void kB(
    const float* __restrict__ x, const unsigned char* __restrict__ v8,
    const float* __restrict__ ref, const unsigned short* __restrict__ wct,
    const float* __restrict__ g1, const float* __restrict__ be1,
    const float* __restrict__ boff, const float* __restrict__ ba,
    const float* __restrict__ Wo, const float* __restrict__ bo,
    float* __restrict__ out)
{
    // float-index regions:
    // [0,4352)      sout[64][68]  (overlays wfa+hb, which die after MFMA)
    // [4352,6656)   locs[64][36]
    // [6656,7936)   LG[64][20]; softmax normalizes IN PLACE (atts = same region)
    __shared__ float ldsf[7936];
    unsigned short* lds16 = (unsigned short*)ldsf;   // wfa: 0..4095, hb: 4096..8191
    const int t = threadIdx.x;
    // XCD-chunked swizzle: 1024 blocks, 8 XCDs, 128 contiguous per XCD
    const int bid = (blockIdx.x & 7) * (NTOK / TOKB / 8) + (blockIdx.x >> 3);
    const int tok0 = bid * TOKB;
    const int b = tok0 >> 15;

    // ---- stage wct cols 64..127 -> lds16[0..4095] (swizzled)
    #pragma unroll
    for (int i = 0; i < 2; ++i) {
        const int q4 = t + i * 256;             // local uint4 idx, 512 total
        const uint4 d = ((const uint4*)wct)[q4 + 512];
        const int u0 = q4 * 4;
        const int c = u0 >> 5;
        const int udst = u0 ^ ((c & 7) << 2);
        *(uint4*)&((unsigned int*)lds16)[udst] = d;
    }
    ln_to_bf16_lds(x, g1, be1, tok0, t, lds16 + 4096);
    __syncthreads();

    // ---- MFMA: wave = M-tile (16 tok); 4 N-tiles (fused cols 64..127)
    const int lane = t & 63, wvid = t >> 6;
    {
        const int fr = lane & 15, kb = (lane >> 4) * 8;
        const int atok = wvid * 16 + fr;
        f32x4v acc[4];
        #pragma unroll
        for (int nt = 0; nt < 4; ++nt) acc[nt] = (f32x4v){0.0f, 0.0f, 0.0f, 0.0f};
        #pragma unroll
        for (int ks = 0; ks < 2; ++ks) {
            const short8v a = *(const short8v*)&lds16[4096 + ((atok * 64 + ks * 32 + kb) ^ ((atok & 7) << 3))];
            #pragma unroll
            for (int nt = 0; nt < 4; ++nt) {
                const int col = nt * 16 + fr;
                const short8v bfr = *(const short8v*)&lds16[(col * 64 + ks * 32 + kb) ^ ((col & 7) << 3)];
                acc[nt] = __builtin_amdgcn_mfma_f32_16x16x32_bf16(a, bfr, acc[nt], 0, 0, 0);
            }
        }
        const int rbase = wvid * 16 + (lane >> 4) * 4;
        #pragma unroll
        for (int nt = 0; nt < 4; ++nt) {
            const int col = nt * 16 + fr;
            if (col < 36) {
                const int rco = (col >= 18) ? col - 18 : col;
                const float bo_ = boff[col];
                #pragma unroll
                for (int r = 0; r < 4; ++r) {
                    const size_t tokg = (size_t)tok0 + rbase + r;
                    ldsf[4352 + (rbase + r) * 36 + col] = ref[tokg * 18 + rco] + acc[nt][r] + bo_;
                }
            } else if (col < 54) {
                const int lg = col - 36;
                const float bav = ba[lg];
                #pragma unroll
                for (int r = 0; r < 4; ++r) ldsf[6656 + (rbase + r) * 20 + lg] = acc[nt][r] + bav;
            }
        }
    }
    __syncthreads();

    // ---- softmax per (token, head): normalize LG in place
    if (t < TOKB * 2) {
        const int tk = t >> 1, head = t & 1;
        float mx = -1e30f;
        #pragma unroll
        for (int k = 0; k < 9; ++k) mx = fmaxf(mx, ldsf[6656 + tk * 20 + head * 9 + k]);
        float e[9], s = 0.0f;
        #pragma unroll
        for (int k = 0; k < 9; ++k) { e[k] = expf(ldsf[6656 + tk * 20 + head * 9 + k] - mx); s += e[k]; }
        const float inv = 1.0f / s;
        #pragma unroll
        for (int k = 0; k < 9; ++k) ldsf[6656 + tk * 20 + head * 9 + k] = e[k] * inv;
    }
    __syncthreads();

    // ---- sampling: lane = half(bit0)|head(bit1)|tok(bits2-5); 16 ch/lane
    {
        const int half = lane & 1;
        const int n = (lane >> 1) & 1;
        const int tkl = wvid * 16 + (lane >> 2);
        const unsigned char* __restrict__ vimg =
            v8 + (size_t)(b * 2 + n) * HWq * 32 + half * 16;

        float a[16];
        #pragma unroll
        for (int j = 0; j < 16; ++j) a[j] = 0.0f;

        #pragma unroll
        for (int k = 0; k < 9; ++k) {
            const float2 g = *(const float2*)&ldsf[4352 + tkl * 36 + n * 18 + 2 * k];
            const float at = ldsf[6656 + tkl * 20 + n * 9 + k];
            const float ix = fmaf(g.x, 128.0f, 127.5f);
            const float iy = fmaf(g.y, 64.0f, 63.5f);
            const float x0f = floorf(ix), y0f = floorf(iy);
            const float wx1 = ix - x0f, wy1 = iy - y0f;
            const float wx0 = 1.0f - wx1, wy0 = 1.0f - wy1;
            const int x0 = (int)x0f, y0 = (int)y0f;
            const int x1i = x0 + 1, y1i = y0 + 1;
            const int x0c = min(max(x0, 0), Wq - 1), y0c = min(max(y0, 0), Hq - 1);
            const int x1c = min(max(x1i, 0), Wq - 1), y1c = min(max(y1i, 0), Hq - 1);
            const bool vx0 = (x0 >= 0) & (x0 <= Wq - 1);
            const bool vy0 = (y0 >= 0) & (y0 <= Hq - 1);
            const bool vx1 = (x1i >= 0) & (x1i <= Wq - 1);
            const bool vy1 = (y1i >= 0) & (y1i <= Hq - 1);
            const float ax0 = at * wx0, ax1 = at * wx1;
            const float w00 = (vx0 && vy0) ? ax0 * wy0 : 0.0f;
            const float w10 = (vx1 && vy0) ? ax1 * wy0 : 0.0f;
            const float w01 = (vx0 && vy1) ? ax0 * wy1 : 0.0f;
            const float w11 = (vx1 && vy1) ? ax1 * wy1 : 0.0f;
            const int p00 = (((y0c << 8) + x0c) << 5), p10 = (((y0c << 8) + x1c) << 5);
            const int p01 = (((y1c << 8) + x0c) << 5), p11 = (((y1c << 8) + x1c) << 5);
            const uint4v q00 = *(const uint4v*)(vimg + p00);
            const uint4v q10 = *(const uint4v*)(vimg + p10);
            const uint4v q01 = *(const uint4v*)(vimg + p01);
            const uint4v q11 = *(const uint4v*)(vimg + p11);
            #pragma unroll
            for (int j = 0; j < 4; ++j) {
                {
                    auto lo = __builtin_amdgcn_cvt_pk_f32_fp8(q00[j], false);
                    auto hi = __builtin_amdgcn_cvt_pk_f32_fp8(q00[j], true);
                    a[4*j+0] = fmaf(w00, lo[0], a[4*j+0]); a[4*j+1] = fmaf(w00, lo[1], a[4*j+1]);
                    a[4*j+2] = fmaf(w00, hi[0], a[4*j+2]); a[4*j+3] = fmaf(w00, hi[1], a[4*j+3]);
                }
                {
                    auto lo = __builtin_amdgcn_cvt_pk_f32_fp8(q10[j], false);
                    auto hi = __builtin_amdgcn_cvt_pk_f32_fp8(q10[j], true);
                    a[4*j+0] = fmaf(w10, lo[0], a[4*j+0]); a[4*j+1] = fmaf(w10, lo[1], a[4*j+1]);
                    a[4*j+2] = fmaf(w10, hi[0], a[4*j+2]); a[4*j+3] = fmaf(w10, hi[1], a[4*j+3]);
                }
                {
                    auto lo = __builtin_amdgcn_cvt_pk_f32_fp8(q01[j], false);
                    auto hi = __builtin_amdgcn_cvt_pk_f32_fp8(q01[j], true);
                    a[4*j+0] = fmaf(w01, lo[0], a[4*j+0]); a[4*j+1] = fmaf(w01, lo[1], a[4*j+1]);
                    a[4*j+2] = fmaf(w01, hi[0], a[4*j+2]); a[4*j+3] = fmaf(w01, hi[1], a[4*j+3]);
                }
                {
                    auto lo = __builtin_amdgcn_cvt_pk_f32_fp8(q11[j], false);
                    auto hi = __builtin_amdgcn_cvt_pk_f32_fp8(q11[j], true);
                    a[4*j+0] = fmaf(w11, lo[0], a[4*j+0]); a[4*j+1] = fmaf(w11, lo[1], a[4*j+1]);
                    a[4*j+2] = fmaf(w11, hi[0], a[4*j+2]); a[4*j+3] = fmaf(w11, hi[1], a[4*j+3]);
                }
            }
        }
        const int ch0 = n * 32 + half * 16;
        float4 o0 = {a[0], a[1], a[2], a[3]};
        float4 o1 = {a[4], a[5], a[6], a[7]};
        float4 o2 = {a[8], a[9], a[10], a[11]};
        float4 o3 = {a[12], a[13], a[14], a[15]};
        *(float4*)&ldsf[tkl * 68 + ch0 + 0]  = o0;
        *(float4*)&ldsf[tkl * 68 + ch0 + 4]  = o1;
        *(float4*)&ldsf[tkl * 68 + ch0 + 8]  = o2;
        *(float4*)&ldsf[tkl * 68 + ch0 + 12] = o3;
    }
    __syncthreads();

    // ---- Wo GEMM: thread -> 2 tokens (t>>3), 8 cols ((t&7)*8); Wo via L1
    const int tg = t >> 3, cg8 = t & 7;
    const int tb = tg * 2, cb = cg8 * 8;
    float accw[2][8];
    #pragma unroll
    for (int i = 0; i < 2; ++i)
        #pragma unroll
        for (int q = 0; q < 8; ++q) accw[i][q] = 0.0f;

    for (int j = 0; j < 64; j += 4) {
        const float4 h0 = *(const float4*)&ldsf[(tb + 0) * 68 + j];
        const float4 h1 = *(const float4*)&ldsf[(tb + 1) * 68 + j];
        const float hv[2][4] = {{h0.x,h0.y,h0.z,h0.w},{h1.x,h1.y,h1.z,h1.w}};
        #pragma unroll
        for (int jj = 0; jj < 4; ++jj) {
            const float4 wA = *(const float4*)&Wo[(size_t)(j + jj) * 64 + cb];
            const float4 wB = *(const float4*)&Wo[(size_t)(j + jj) * 64 + cb + 4];
            const float wv8[8] = {wA.x,wA.y,wA.z,wA.w,wB.x,wB.y,wB.z,wB.w};
            #pragma unroll
            for (int i = 0; i < 2; ++i)
                #pragma unroll
                for (int q = 0; q < 8; ++q)
                    accw[i][q] = fmaf(hv[i][jj], wv8[q], accw[i][q]);
        }
    }
    const float4 boA = *(const float4*)&bo[cb];
    const float4 boB = *(const float4*)&bo[cb + 4];
    #pragma unroll
    for (int i = 0; i < 2; ++i) {
        const size_t tokg = (size_t)tok0 + tb + i;
        const float4 rA = *(const float4*)&x[tokg * 64 + cb];
        const float4 rB = *(const float4*)&x[tokg * 64 + cb + 4];
        float4 oA = {accw[i][0]+boA.x+rA.x, accw[i][1]+boA.y+rA.y,
                     accw[i][2]+boA.z+rA.z, accw[i][3]+boA.w+rA.w};
        float4 oB = {accw[i][4]+boB.x+rB.x, accw[i][5]+boB.y+rB.y,
                     accw[i][6]+boB.z+rB.z, accw[i][7]+boB.w+rB.w};
        *(float4*)&out[tokg * 64 + cb] = oA;
        *(float4*)&out[tokg * 64 + cb + 4] = oB;
    }
}

// ============ Kernel C: LN2 + bf16 MFMA W1 + GELU -> y (fp8) =================
// 512 threads (8 waves), 64 tokens/block.
__global__ __launch_bounds__(512) void kC(
    const float* __restrict__ x1, const float* __restrict__ g2, const float* __restrict__ be2,
    const unsigned short* __restrict__ w1t, const float* __restrict__ c1,
    unsigned char* __restrict__ y8)
{
    __shared__ unsigned short W1T[256 * 64];    // bf16 [col][k], swizzled (32 KB)
    __shared__ unsigned short hb2[TOKC * 64];   // bf16 [tok][k], swizzled (8 KB)
    __shared__ unsigned char ytile8[TOKC * 256];// fp8 [tok][col], swizzled (16 KB)
    const int t = threadIdx.x;
    const int tok0 = blockIdx.x * TOKC;

    #pragma unroll
    for (int i = 0; i < 4; ++i) {
        const int q4 = t + i * 512;
        const uint4 d = ((const uint4*)w1t)[q4];
        const int u0 = q4 * 4;
        const int c = u0 >> 5;
        const int udst = u0 ^ ((c & 7) << 2);
        *(uint4*)&((unsigned int*)W1T)[udst] = d;
    }
    if (t < TOKC * 4) ln_to_bf16_lds(x1, g2, be2, tok0, t, hb2);
    __syncthreads();

    const int lane = t & 63, wv = t >> 6;
    const int mtile = wv & 3, nquad = wv >> 2;
    const int fr = lane & 15, kb = (lane >> 4) * 8;
    const int atok = mtile * 16 + fr;
    f32x4v acc[8];
    #pragma unroll
    for (int nt = 0; nt < 8; ++nt) acc[nt] = (f32x4v){0.0f, 0.0f, 0.0f, 0.0f};

    #pragma unroll
    for (int ks = 0; ks < 2; ++ks) {
        const short8v a = *(const short8v*)&hb2[(atok * 64 + ks * 32 + kb) ^ ((atok & 7) << 3)];
        #pragma unroll
        for (int nt = 0; nt < 8; ++nt) {
            const int col = nquad * 128 + nt * 16 + fr;
            const short8v bfr = *(const short8v*)&W1T[(col * 64 + ks * 32 + kb) ^ ((col & 7) << 3)];
            acc[nt] = __builtin_amdgcn_mfma_f32_16x16x32_bf16(a, bfr, acc[nt], 0, 0, 0);
        }
    }

    #pragma unroll
    for (int nt = 0; nt < 8; ++nt) {
        const int col = nquad * 128 + nt * 16 + fr;
        const float c1v = c1[col];
        #pragma unroll
        for (int r = 0; r < 4; ++r) {
            const int tok = mtile * 16 + (lane >> 4) * 4 + r;
            const float val = gelu_exact(acc[nt][r] + c1v);
            const int pk = __builtin_amdgcn_cvt_pk_fp8_f32(val, val, 0, false);
            ytile8[((unsigned)(tok * 256 + col)) ^ (((unsigned)(tok & 7)) << 4)] = (unsigned char)(pk & 0xFF);
        }
    }
    __syncthreads();

    {
        const int row = t >> 3, cb = (t & 7) * 32;
        const unsigned int swz = ((unsigned int)(row & 7)) << 4;
        unsigned char* dst = y8 + (size_t)(tok0 + row) * 256 + cb;
        #pragma unroll
        for (int j = 0; j < 2; ++j) {
            const unsigned int bidx = ((unsigned int)(row * 256 + cb + j * 16)) ^ swz;
            *(uint4*)(dst + j * 16) = *(const uint4*)&ytile8[bidx];
        }
    }
}

// ============ Kernel D: depthwise 3x3 (fp8 y) + GELU + MFMA W2 ===============
// 256 threads. LDS: zsb2 only (16 KB) -> high occupancy.
__global__ __launch_bounds__(256) void kD(
    const unsigned char* __restrict__ y8, const float* __restrict__ Wdw, const float* __restrict__ bdw,
    const unsigned short* __restrict__ w2t, const float* __restrict__ c2,
    float* __restrict__ out)
{
    __shared__ unsigned short zsb2[PIXD * 256]; // bf16 [pix][k], swizzled (16 KB)
    const int t = threadIdx.x;
    const int bid = (blockIdx.x & 7) * 256 + (blockIdx.x >> 3);
    const int b = bid >> 10;
    const int rem = bid & 1023;
    const int hh = rem >> 3;
    const int ww0 = (rem & 7) * PIXD;

    {
        const int lane = t & 63, sub = t >> 6;
        const int c4 = lane * 4;
        const int px0 = ww0 + sub * 8;
        const unsigned char* __restrict__ yb = y8 + (size_t)b * HWq * 256;
        const bool r0ok = (hh > 0), r2ok = (hh < Hq - 1);
        const int y0r = (hh - 1) << 8, y1r = hh << 8, y2r = (hh + 1) << 8;

        float um1[3][4], uz0[3][4], up1[3][4];
        #define LOADCOL(dst, xx) do {                                              \
            const unsigned int u0v = r0ok ? *(const unsigned int*)&yb[((size_t)(y0r + (xx)) << 8) + c4] : 0u; \
            const unsigned int u1v =        *(const unsigned int*)&yb[((size_t)(y1r + (xx)) << 8) + c4]; \
            const unsigned int u2v = r2ok ? *(const unsigned int*)&yb[((size_t)(y2r + (xx)) << 8) + c4] : 0u; \
            { auto lo = __builtin_amdgcn_cvt_pk_f32_fp8(u0v, false);               \
              auto hi = __builtin_amdgcn_cvt_pk_f32_fp8(u0v, true);                \
              dst[0][0] = lo[0]; dst[0][1] = lo[1]; dst[0][2] = hi[0]; dst[0][3] = hi[1]; } \
            { auto lo = __builtin_amdgcn_cvt_pk_f32_fp8(u1v, false);               \
              auto hi = __builtin_amdgcn_cvt_pk_f32_fp8(u1v, true);                \
              dst[1][0] = lo[0]; dst[1][1] = lo[1]; dst[1][2] = hi[0]; dst[1][3] = hi[1]; } \
            { auto lo = __builtin_amdgcn_cvt_pk_f32_fp8(u2v, false);               \
              auto hi = __builtin_amdgcn_cvt_pk_f32_fp8(u2v, true);                \
              dst[2][0] = lo[0]; dst[2][1] = lo[1]; dst[2][2] = hi[0]; dst[2][3] = hi[1]; } \
        } while (0)

        float wd[9][4], bdv[4];
        #pragma unroll
        for (int j = 0; j < 4; ++j) {
            bdv[j] = bdw[c4 + j];
            #pragma unroll
            for (int q = 0; q < 9; ++q) wd[q][j] = Wdw[(c4 + j) * 9 + q];
        }

        LOADCOL(um1, (px0 - 1) & 255);
        LOADCOL(uz0, px0);
        #pragma unroll
        for (int p = 0; p < 8; ++p) {
            LOADCOL(up1, (px0 + p + 1) & 255);
            unsigned short zq[4];
            #pragma unroll
            for (int j = 0; j < 4; ++j) {
                float a = bdv[j];
                #pragma unroll
                for (int ky = 0; ky < 3; ++ky) {
                    a = fmaf(wd[ky * 3 + 0][j], um1[ky][j], a);
                    a = fmaf(wd[ky * 3 + 1][j], uz0[ky][j], a);
                    a = fmaf(wd[ky * 3 + 2][j], up1[ky][j], a);
                }
                zq[j] = f2bf(gelu_exact(a));
            }
            const int pix = sub * 8 + p;
            ushort4v zv = {zq[0], zq[1], zq[2], zq[3]};
            *(ushort4v*)&zsb2[((unsigned)(pix * 256 + c4)) ^ (((unsigned)(pix & 7)) << 3)] = zv;
            #pragma unroll
            for (int ky = 0; ky < 3; ++ky)
                #pragma unroll
                for (int j = 0; j < 4; ++j) { um1[ky][j] = uz0[ky][j]; uz0[ky][j] = up1[ky][j]; }
        }
        #undef LOADCOL
    }
    __syncthreads();

    const int lane = t & 63, wv = t >> 6;
    const int fr = lane & 15;
    const int kb = (lane >> 4) * 8;
    const int col = wv * 16 + fr;
    f32x4v acc0 = {0.0f, 0.0f, 0.0f, 0.0f};
    f32x4v acc1 = {0.0f, 0.0f, 0.0f, 0.0f};
    #pragma unroll
    for (int kk = 0; kk < 8; ++kk) {
        const int ka = kk * 32 + kb;
        const short8v bfr = *(const short8v*)&w2t[(size_t)col * 256 + ka];
        const short8v a0 = *(const short8v*)&zsb2[(fr * 256 + ka) ^ ((fr & 7) << 3)];
        const short8v a1 = *(const short8v*)&zsb2[((fr + 16) * 256 + ka) ^ ((fr & 7) << 3)];
        acc0 = __builtin_amdgcn_mfma_f32_16x16x32_bf16(a0, bfr, acc0, 0, 0, 0);
        acc1 = __builtin_amdgcn_mfma_f32_16x16x32_bf16(a1, bfr, acc1, 0, 0, 0);
    }
    const float c2v = c2[col];
    #pragma unroll
    for (int r = 0; r < 4; ++r) {
        const int prow = (lane >> 4) * 4 + r;
        const size_t tok0g = (size_t)b * HWq + ((size_t)hh << 8) + ww0;
        out[(tok0g + prow) * 64 + col] += acc0[r] + c2v;
        out[(tok0g + 16 + prow) * 64 + col] += acc1[r] + c2v;
    }
}

extern "C" void kernel_launch(void* const* d_in, const int* in_sizes, int n_in,
                              void* d_out, int out_size, void* d_ws, size_t ws_size,
                              hipStream_t stream) {
    const float* x    = (const float*)d_in[0];
    const float* ref  = (const float*)d_in[1];
    const float* g1   = (const float*)d_in[2];
    const float* be1  = (const float*)d_in[3];
    const float* g2   = (const float*)d_in[4];
    const float* be2  = (const float*)d_in[5];
    const float* Woff = (const float*)d_in[6];
    const float* boff = (const float*)d_in[7];
    const float* Wa   = (const float*)d_in[8];
    const float* ba   = (const float*)d_in[9];
    const float* Wv   = (const float*)d_in[10];
    const float* bv   = (const float*)d_in[11];
    const float* Wo   = (const float*)d_in[12];
    const float* bo   = (const float*)d_in[13];
    const float* W1   = (const float*)d_in[14];
    const float* c1   = (const float*)d_in[15];
    const float* Wdw  = (const float*)d_in[16];
    const float* bdw  = (const float*)d_in[17];
    const float* W2   = (const float*)d_in[18];
    const float* c2   = (const float*)d_in[19];

    float* out = (float*)d_out;
    unsigned char* wsb = (unsigned char*)d_ws;
    unsigned char* v8 = wsb;                                        // 4 MB
    unsigned char* y8 = v8 + (size_t)Bq * 2 * HWq * 32;             // 16.8 MB
    unsigned short* w1t = (unsigned short*)(y8 + (size_t)NTOK * 256);
    unsigned short* w2t = w1t + 256 * 64;
    unsigned short* wct = w2t + 64 * 256;

    hipLaunchKernelGGL(kPrep, dim3(80), dim3(256), 0, stream,
                       W1, W2, Wv, Woff, Wa, w1t, w2t, wct);
    hipLaunchKernelGGL(kA, dim3(NTOK / TOKA), dim3(256), 0, stream,
                       x, g1, be1, wct, bv, v8);
    hipLaunchKernelGGL(kB, dim3(NTOK / TOKB), dim3(256), 0, stream,
                       x, v8, ref, wct, g1, be1, boff, ba, Wo, bo, out);
    hipLaunchKernelGGL(kC, dim3(NTOK / TOKC), dim3(512), 0, stream,
                       out, g2, be2, w1t, c1, y8);
    hipLaunchKernelGGL(kD, dim3(Bq * Hq * (Wq / PIXD)), dim3(256), 0, stream,
                       y8, Wdw, bdw, w2t, c2, out);
}

// Round 20
// 88.076 us; speedup vs baseline: 1.5241x; 1.1305x over previous
//
#include <hip/hip_runtime.h>
#include <math.h>

#define Bq 2
#define Hq 128
#define Wq 256
#define Cq 64
#define HIDq 256
#define HWq (Hq * Wq)
#define NTOK (Bq * HWq)

#define TOKA 64
#define TOKB 64
#define TOKC 64
#define PIXD 32

typedef __attribute__((ext_vector_type(8))) short short8v;
typedef __attribute__((ext_vector_type(4))) float f32x4v;
typedef __attribute__((ext_vector_type(4))) unsigned short ushort4v;
typedef __attribute__((ext_vector_type(4))) unsigned int uint4v;

__device__ inline float gelu_exact(float x) {
    return 0.5f * x * (1.0f + erff(x * 0.70710678118654752440f));
}

__device__ inline unsigned short f2bf(float f) {
    unsigned int u = __float_as_uint(f);
    u += 0x7FFFu + ((u >> 16) & 1u);
    return (unsigned short)(u >> 16);
}

__device__ inline float bf2f(unsigned short u) {
    return __uint_as_float(((unsigned int)u) << 16);
}

// ============ Kernel P: pack weights -> bf16 transposed [col][k] in ws =======
__global__ __launch_bounds__(256) void kPrep(
    const float* __restrict__ W1, const float* __restrict__ W2,
    const float* __restrict__ Wv, const float* __restrict__ Woff, const float* __restrict__ Wa,
    const float* __restrict__ Wo,
    unsigned short* __restrict__ w1t, unsigned short* __restrict__ w2t,
    unsigned short* __restrict__ wct, unsigned short* __restrict__ wot)
{
    const int p = blockIdx.x * 256 + threadIdx.x;    // 88*256 = 22528
    if (p < 8192) {                                  // W1T: c 0..255, k2 0..31
        const int c = p >> 5, k2 = p & 31;
        const unsigned int pk = (unsigned int)f2bf(W1[(size_t)(2 * k2) * 256 + c])
                              | ((unsigned int)f2bf(W1[(size_t)(2 * k2 + 1) * 256 + c]) << 16);
        ((unsigned int*)w1t)[c * 32 + k2] = pk;
    } else if (p < 16384) {                          // W2T: c 0..63, k2 0..127
        const int q = p - 8192;
        const int c = q >> 7, k2 = q & 127;
        const unsigned int pk = (unsigned int)f2bf(W2[(size_t)(2 * k2) * 64 + c])
                              | ((unsigned int)f2bf(W2[(size_t)(2 * k2 + 1) * 64 + c]) << 16);
        ((unsigned int*)w2t)[c * 128 + k2] = pk;
    } else if (p < 20480) {                          // WcT: c 0..127, k2 0..31
        const int q = p - 16384;
        const int c = q >> 5, k2 = q & 31;
        float w0 = 0.0f, w1 = 0.0f;
        if (c < 64)       { w0 = Wv[(size_t)(2 * k2) * 64 + c];          w1 = Wv[(size_t)(2 * k2 + 1) * 64 + c]; }
        else if (c < 100) { w0 = Woff[(size_t)(2 * k2) * 36 + (c - 64)]; w1 = Woff[(size_t)(2 * k2 + 1) * 36 + (c - 64)]; }
        else if (c < 118) { w0 = Wa[(size_t)(2 * k2) * 18 + (c - 100)];  w1 = Wa[(size_t)(2 * k2 + 1) * 18 + (c - 100)]; }
        const unsigned int pk = (unsigned int)f2bf(w0) | ((unsigned int)f2bf(w1) << 16);
        ((unsigned int*)wct)[c * 32 + k2] = pk;
    } else {                                         // WoT: c 0..63, k2 0..31
        const int q = p - 20480;
        const int c = q >> 5, k2 = q & 31;
        const unsigned int pk = (unsigned int)f2bf(Wo[(size_t)(2 * k2) * 64 + c])
                              | ((unsigned int)f2bf(Wo[(size_t)(2 * k2 + 1) * 64 + c]) << 16);
        ((unsigned int*)wot)[c * 32 + k2] = pk;
    }
}

// ============ shared LN helper: thread=(tok,quarter) -> bf16 swizzled LDS ====
__device__ inline void ln_to_bf16_lds(
    const float* __restrict__ xsrc, const float* __restrict__ g, const float* __restrict__ be,
    int tok0, int t, unsigned short* __restrict__ hdst)
{
    const int tok = t >> 2, part = t & 3;
    const int chb = part * 16;
    const float* xp = xsrc + (size_t)(tok0 + tok) * 64 + chb;
    const float4 v0 = ((const float4*)xp)[0];
    const float4 v1 = ((const float4*)xp)[1];
    const float4 v2 = ((const float4*)xp)[2];
    const float4 v3 = ((const float4*)xp)[3];
    float s = ((v0.x + v0.y) + (v0.z + v0.w)) + ((v1.x + v1.y) + (v1.z + v1.w))
            + ((v2.x + v2.y) + (v2.z + v2.w)) + ((v3.x + v3.y) + (v3.z + v3.w));
    float s2 = 0.0f;
    s2 = fmaf(v0.x, v0.x, s2); s2 = fmaf(v0.y, v0.y, s2);
    s2 = fmaf(v0.z, v0.z, s2); s2 = fmaf(v0.w, v0.w, s2);
    s2 = fmaf(v1.x, v1.x, s2); s2 = fmaf(v1.y, v1.y, s2);
    s2 = fmaf(v1.z, v1.z, s2); s2 = fmaf(v1.w, v1.w, s2);
    s2 = fmaf(v2.x, v2.x, s2); s2 = fmaf(v2.y, v2.y, s2);
    s2 = fmaf(v2.z, v2.z, s2); s2 = fmaf(v2.w, v2.w, s2);
    s2 = fmaf(v3.x, v3.x, s2); s2 = fmaf(v3.y, v3.y, s2);
    s2 = fmaf(v3.z, v3.z, s2); s2 = fmaf(v3.w, v3.w, s2);
    s  += __shfl_xor(s, 1);  s2 += __shfl_xor(s2, 1);
    s  += __shfl_xor(s, 2);  s2 += __shfl_xor(s2, 2);
    const float m  = s * (1.0f / 64.0f);
    const float var = fmaf(-m, m, s2 * (1.0f / 64.0f));
    const float rs = rsqrtf(var + 1e-5f);
    const float nb = -m * rs;
    const float vv[16] = {v0.x,v0.y,v0.z,v0.w, v1.x,v1.y,v1.z,v1.w,
                          v2.x,v2.y,v2.z,v2.w, v3.x,v3.y,v3.z,v3.w};
    unsigned int pk[8];
    #pragma unroll
    for (int q = 0; q < 8; ++q) {
        const float hA = fmaf(fmaf(vv[2*q], rs, nb), g[chb + 2*q], be[chb + 2*q]);
        const float hB = fmaf(fmaf(vv[2*q+1], rs, nb), g[chb + 2*q+1], be[chb + 2*q+1]);
        pk[q] = (unsigned int)f2bf(hA) | ((unsigned int)f2bf(hB) << 16);
    }
    const unsigned int swz = ((unsigned int)(tok & 7)) << 3;
    unsigned int hi0 = ((unsigned int)(tok * 64 + chb)) ^ swz;
    unsigned int hi1 = ((unsigned int)(tok * 64 + chb + 8)) ^ swz;
    uint4 gA = {pk[0], pk[1], pk[2], pk[3]};
    uint4 gB = {pk[4], pk[5], pk[6], pk[7]};
    *(uint4*)&hdst[hi0] = gA;
    *(uint4*)&hdst[hi1] = gB;
}

// ============ Kernel A: LN1 + bf16 MFMA Wv -> v8 (fp8) =======================
// 256 threads (4 waves), 64 tokens/block.
__global__ __launch_bounds__(256) void kA(
    const float* __restrict__ x,
    const float* __restrict__ g1, const float* __restrict__ be1,
    const unsigned short* __restrict__ wct, const float* __restrict__ bv,
    unsigned char* __restrict__ v8)
{
    __shared__ unsigned short WvT[64 * 64];      // bf16 [col][k], swizzled (8 KB)
    __shared__ unsigned short hb[TOKA * 64];     // bf16 [tok][k], swizzled (8 KB)
    __shared__ unsigned char vtile[TOKA * 64];   // fp8 [tok][ch] (4 KB)
    const int t = threadIdx.x;
    const int tok0 = blockIdx.x * TOKA;
    const int b = tok0 >> 15;
    const int pix0 = tok0 & (HWq - 1);

    #pragma unroll
    for (int i = 0; i < 2; ++i) {
        const int q4 = t + i * 256;
        const uint4 d = ((const uint4*)wct)[q4];
        const int u0 = q4 * 4;
        const int c = u0 >> 5;
        const int udst = u0 ^ ((c & 7) << 2);
        *(uint4*)&((unsigned int*)WvT)[udst] = d;
    }
    ln_to_bf16_lds(x, g1, be1, tok0, t, hb);
    __syncthreads();

    const int lane = t & 63, wv = t >> 6;
    const int fr = lane & 15, kb = (lane >> 4) * 8;
    const int atok = wv * 16 + fr;
    f32x4v acc[4];
    #pragma unroll
    for (int nt = 0; nt < 4; ++nt) acc[nt] = (f32x4v){0.0f, 0.0f, 0.0f, 0.0f};
    #pragma unroll
    for (int ks = 0; ks < 2; ++ks) {
        const short8v a = *(const short8v*)&hb[(atok * 64 + ks * 32 + kb) ^ ((atok & 7) << 3)];
        #pragma unroll
        for (int nt = 0; nt < 4; ++nt) {
            const int col = nt * 16 + fr;
            const short8v bfr = *(const short8v*)&WvT[(col * 64 + ks * 32 + kb) ^ ((col & 7) << 3)];
            acc[nt] = __builtin_amdgcn_mfma_f32_16x16x32_bf16(a, bfr, acc[nt], 0, 0, 0);
        }
    }
    const int rbase = wv * 16 + (lane >> 4) * 4;
    #pragma unroll
    for (int nt = 0; nt < 4; ++nt) {
        const int col = nt * 16 + fr;
        const float bvv = bv[col];
        #pragma unroll
        for (int r = 0; r < 4; ++r) {
            const float val = acc[nt][r] + bvv;
            const int pk = __builtin_amdgcn_cvt_pk_fp8_f32(val, val, 0, false);
            vtile[(rbase + r) * 64 + col] = (unsigned char)(pk & 0xFF);
        }
    }
    __syncthreads();

    {
        const int tok = t >> 2, chunk = t & 3;
        const int n = chunk >> 1;
        const uint4 d = *(const uint4*)&vtile[tok * 64 + chunk * 16];
        *(uint4*)&v8[((size_t)(b * 2 + n) * HWq + pix0 + tok) * 32 + (chunk & 1) * 16] = d;
    }
}

// ============ Kernel B: LN1 + MFMA {Woff|Wa} + softmax + sample + MFMA Wo ====
// 256 threads (4 waves), 64 tokens/block. LDS 31744 B with region reuse:
//   lds16[0..4095]    wfa -> (after P2) woT
//   lds16[4096..8191] hb  -> (after P2) sout bf16 (hb-swizzled layout)
//   ldsf[4352,6656)   locs[64][36]
//   ldsf[6656,7936)   LG[64][20]; softmax normalizes in place
__global__ __launch_bounds__(256) void kB(
    const float* __restrict__ x, const unsigned char* __restrict__ v8,
    const float* __restrict__ ref, const unsigned short* __restrict__ wct,
    const unsigned short* __restrict__ wot,
    const float* __restrict__ g1, const float* __restrict__ be1,
    const float* __restrict__ boff, const float* __restrict__ ba,
    const float* __restrict__ bo, float* __restrict__ out)
{
    __shared__ float ldsf[7936];
    unsigned short* lds16 = (unsigned short*)ldsf;
    const int t = threadIdx.x;
    // XCD-chunked swizzle: 1024 blocks, 8 XCDs, 128 contiguous per XCD
    const int bid = (blockIdx.x & 7) * (NTOK / TOKB / 8) + (blockIdx.x >> 3);
    const int tok0 = bid * TOKB;
    const int b = tok0 >> 15;

    // ---- P1: stage wct cols 64..127 -> wfa; LN1 -> hb
    #pragma unroll
    for (int i = 0; i < 2; ++i) {
        const int q4 = t + i * 256;
        const uint4 d = ((const uint4*)wct)[q4 + 512];
        const int u0 = q4 * 4;
        const int c = u0 >> 5;
        const int udst = u0 ^ ((c & 7) << 2);
        *(uint4*)&((unsigned int*)lds16)[udst] = d;
    }
    ln_to_bf16_lds(x, g1, be1, tok0, t, lds16 + 4096);
    __syncthreads();

    // ---- P2: MFMA offsets -> locs, LG
    const int lane = t & 63, wvid = t >> 6;
    {
        const int fr = lane & 15, kb = (lane >> 4) * 8;
        const int atok = wvid * 16 + fr;
        f32x4v acc[4];
        #pragma unroll
        for (int nt = 0; nt < 4; ++nt) acc[nt] = (f32x4v){0.0f, 0.0f, 0.0f, 0.0f};
        #pragma unroll
        for (int ks = 0; ks < 2; ++ks) {
            const short8v a = *(const short8v*)&lds16[4096 + ((atok * 64 + ks * 32 + kb) ^ ((atok & 7) << 3))];
            #pragma unroll
            for (int nt = 0; nt < 4; ++nt) {
                const int col = nt * 16 + fr;
                const short8v bfr = *(const short8v*)&lds16[(col * 64 + ks * 32 + kb) ^ ((col & 7) << 3)];
                acc[nt] = __builtin_amdgcn_mfma_f32_16x16x32_bf16(a, bfr, acc[nt], 0, 0, 0);
            }
        }
        const int rbase = wvid * 16 + (lane >> 4) * 4;
        #pragma unroll
        for (int nt = 0; nt < 4; ++nt) {
            const int col = nt * 16 + fr;
            if (col < 36) {
                const int rco = (col >= 18) ? col - 18 : col;
                const float bo_ = boff[col];
                #pragma unroll
                for (int r = 0; r < 4; ++r) {
                    const size_t tokg = (size_t)tok0 + rbase + r;
                    ldsf[4352 + (rbase + r) * 36 + col] = ref[tokg * 18 + rco] + acc[nt][r] + bo_;
                }
            } else if (col < 54) {
                const int lg = col - 36;
                const float bav = ba[lg];
                #pragma unroll
                for (int r = 0; r < 4; ++r) ldsf[6656 + (rbase + r) * 20 + lg] = acc[nt][r] + bav;
            }
        }
    }
    __syncthreads();

    // ---- P3: softmax in place; stage woT into dead wfa region
    #pragma unroll
    for (int i = 0; i < 2; ++i) {
        const int q4 = t + i * 256;
        const uint4 d = ((const uint4*)wot)[q4];
        const int u0 = q4 * 4;
        const int c = u0 >> 5;
        const int udst = u0 ^ ((c & 7) << 2);
        *(uint4*)&((unsigned int*)lds16)[udst] = d;
    }
    if (t < TOKB * 2) {
        const int tk = t >> 1, head = t & 1;
        float mx = -1e30f;
        #pragma unroll
        for (int k = 0; k < 9; ++k) mx = fmaxf(mx, ldsf[6656 + tk * 20 + head * 9 + k]);
        float e[9], s = 0.0f;
        #pragma unroll
        for (int k = 0; k < 9; ++k) { e[k] = expf(ldsf[6656 + tk * 20 + head * 9 + k] - mx); s += e[k]; }
        const float inv = 1.0f / s;
        #pragma unroll
        for (int k = 0; k < 9; ++k) ldsf[6656 + tk * 20 + head * 9 + k] = e[k] * inv;
    }
    __syncthreads();

    // ---- P4: sampling -> sout bf16 (hb-swizzled) into dead hb region
    {
        const int half = lane & 1;
        const int n = (lane >> 1) & 1;
        const int tkl = wvid * 16 + (lane >> 2);
        const unsigned char* __restrict__ vimg =
            v8 + (size_t)(b * 2 + n) * HWq * 32 + half * 16;

        float a[16];
        #pragma unroll
        for (int j = 0; j < 16; ++j) a[j] = 0.0f;

        #pragma unroll
        for (int k = 0; k < 9; ++k) {
            const float2 g = *(const float2*)&ldsf[4352 + tkl * 36 + n * 18 + 2 * k];
            const float at = ldsf[6656 + tkl * 20 + n * 9 + k];
            const float ix = fmaf(g.x, 128.0f, 127.5f);
            const float iy = fmaf(g.y, 64.0f, 63.5f);
            const float x0f = floorf(ix), y0f = floorf(iy);
            const float wx1 = ix - x0f, wy1 = iy - y0f;
            const float wx0 = 1.0f - wx1, wy0 = 1.0f - wy1;
            const int x0 = (int)x0f, y0 = (int)y0f;
            const int x1i = x0 + 1, y1i = y0 + 1;
            const int x0c = min(max(x0, 0), Wq - 1), y0c = min(max(y0, 0), Hq - 1);
            const int x1c = min(max(x1i, 0), Wq - 1), y1c = min(max(y1i, 0), Hq - 1);
            const bool vx0 = (x0 >= 0) & (x0 <= Wq - 1);
            const bool vy0 = (y0 >= 0) & (y0 <= Hq - 1);
            const bool vx1 = (x1i >= 0) & (x1i <= Wq - 1);
            const bool vy1 = (y1i >= 0) & (y1i <= Hq - 1);
            const float ax0 = at * wx0, ax1 = at * wx1;
            const float w00 = (vx0 && vy0) ? ax0 * wy0 : 0.0f;
            const float w10 = (vx1 && vy0) ? ax1 * wy0 : 0.0f;
            const float w01 = (vx0 && vy1) ? ax0 * wy1 : 0.0f;
            const float w11 = (vx1 && vy1) ? ax1 * wy1 : 0.0f;
            const int p00 = (((y0c << 8) + x0c) << 5), p10 = (((y0c << 8) + x1c) << 5);
            const int p01 = (((y1c << 8) + x0c) << 5), p11 = (((y1c << 8) + x1c) << 5);
            const uint4v q00 = *(const uint4v*)(vimg + p00);
            const uint4v q10 = *(const uint4v*)(vimg + p10);
            const uint4v q01 = *(const uint4v*)(vimg + p01);
            const uint4v q11 = *(const uint4v*)(vimg + p11);
            #pragma unroll
            for (int j = 0; j < 4; ++j) {
                {
                    auto lo = __builtin_amdgcn_cvt_pk_f32_fp8(q00[j], false);
                    auto hi = __builtin_amdgcn_cvt_pk_f32_fp8(q00[j], true);
                    a[4*j+0] = fmaf(w00, lo[0], a[4*j+0]); a[4*j+1] = fmaf(w00, lo[1], a[4*j+1]);
                    a[4*j+2] = fmaf(w00, hi[0], a[4*j+2]); a[4*j+3] = fmaf(w00, hi[1], a[4*j+3]);
                }
                {
                    auto lo = __builtin_amdgcn_cvt_pk_f32_fp8(q10[j], false);
                    auto hi = __builtin_amdgcn_cvt_pk_f32_fp8(q10[j], true);
                    a[4*j+0] = fmaf(w10, lo[0], a[4*j+0]); a[4*j+1] = fmaf(w10, lo[1], a[4*j+1]);
                    a[4*j+2] = fmaf(w10, hi[0], a[4*j+2]); a[4*j+3] = fmaf(w10, hi[1], a[4*j+3]);
                }
                {
                    auto lo = __builtin_amdgcn_cvt_pk_f32_fp8(q01[j], false);
                    auto hi = __builtin_amdgcn_cvt_pk_f32_fp8(q01[j], true);
                    a[4*j+0] = fmaf(w01, lo[0], a[4*j+0]); a[4*j+1] = fmaf(w01, lo[1], a[4*j+1]);
                    a[4*j+2] = fmaf(w01, hi[0], a[4*j+2]); a[4*j+3] = fmaf(w01, hi[1], a[4*j+3]);
                }
                {
                    auto lo = __builtin_amdgcn_cvt_pk_f32_fp8(q11[j], false);
                    auto hi = __builtin_amdgcn_cvt_pk_f32_fp8(q11[j], true);
                    a[4*j+0] = fmaf(w11, lo[0], a[4*j+0]); a[4*j+1] = fmaf(w11, lo[1], a[4*j+1]);
                    a[4*j+2] = fmaf(w11, hi[0], a[4*j+2]); a[4*j+3] = fmaf(w11, hi[1], a[4*j+3]);
                }
            }
        }
        // write 16 ch as bf16 pairs in hb-swizzled layout
        const int ch0 = n * 32 + half * 16;
        unsigned int pk[8];
        #pragma unroll
        for (int q = 0; q < 8; ++q)
            pk[q] = (unsigned int)f2bf(a[2*q]) | ((unsigned int)f2bf(a[2*q+1]) << 16);
        const unsigned int swz = ((unsigned int)(tkl & 7)) << 3;
        const unsigned int hi0 = ((unsigned int)(tkl * 64 + ch0)) ^ swz;
        const unsigned int hi1 = ((unsigned int)(tkl * 64 + ch0 + 8)) ^ swz;
        uint4 gA = {pk[0], pk[1], pk[2], pk[3]};
        uint4 gB = {pk[4], pk[5], pk[6], pk[7]};
        *(uint4*)&lds16[4096 + hi0] = gA;
        *(uint4*)&lds16[4096 + hi1] = gB;
    }
    __syncthreads();

    // ---- P5: Wo MFMA (A = sout bf16, B = woT) + bias + residual -> out
    {
        const int fr = lane & 15, kb = (lane >> 4) * 8;
        const int atok = wvid * 16 + fr;
        f32x4v acc[4];
        #pragma unroll
        for (int nt = 0; nt < 4; ++nt) acc[nt] = (f32x4v){0.0f, 0.0f, 0.0f, 0.0f};
        #pragma unroll
        for (int ks = 0; ks < 2; ++ks) {
            const short8v a = *(const short8v*)&lds16[4096 + ((atok * 64 + ks * 32 + kb) ^ ((atok & 7) << 3))];
            #pragma unroll
            for (int nt = 0; nt < 4; ++nt) {
                const int col = nt * 16 + fr;
                const short8v bfr = *(const short8v*)&lds16[(col * 64 + ks * 32 + kb) ^ ((col & 7) << 3)];
                acc[nt] = __builtin_amdgcn_mfma_f32_16x16x32_bf16(a, bfr, acc[nt], 0, 0, 0);
            }
        }
        const int rbase = wvid * 16 + (lane >> 4) * 4;
        #pragma unroll
        for (int nt = 0; nt < 4; ++nt) {
            const int col = nt * 16 + fr;
            const float bov = bo[col];
            #pragma unroll
            for (int r = 0; r < 4; ++r) {
                const size_t tokg = (size_t)tok0 + rbase + r;
                out[tokg * 64 + col] = acc[nt][r] + bov + x[tokg * 64 + col];
            }
        }
    }
}

// ============ Kernel C: LN2 + bf16 MFMA W1 + GELU -> y (fp8) =================
// 512 threads (8 waves), 64 tokens/block.
__global__ __launch_bounds__(512) void kC(
    const float* __restrict__ x1, const float* __restrict__ g2, const float* __restrict__ be2,
    const unsigned short* __restrict__ w1t, const float* __restrict__ c1,
    unsigned char* __restrict__ y8)
{
    __shared__ unsigned short W1T[256 * 64];    // bf16 [col][k], swizzled (32 KB)
    __shared__ unsigned short hb2[TOKC * 64];   // bf16 [tok][k], swizzled (8 KB)
    __shared__ unsigned char ytile8[TOKC * 256];// fp8 [tok][col], swizzled (16 KB)
    const int t = threadIdx.x;
    const int tok0 = blockIdx.x * TOKC;

    #pragma unroll
    for (int i = 0; i < 4; ++i) {
        const int q4 = t + i * 512;
        const uint4 d = ((const uint4*)w1t)[q4];
        const int u0 = q4 * 4;
        const int c = u0 >> 5;
        const int udst = u0 ^ ((c & 7) << 2);
        *(uint4*)&((unsigned int*)W1T)[udst] = d;
    }
    if (t < TOKC * 4) ln_to_bf16_lds(x1, g2, be2, tok0, t, hb2);
    __syncthreads();

    const int lane = t & 63, wv = t >> 6;
    const int mtile = wv & 3, nquad = wv >> 2;
    const int fr = lane & 15, kb = (lane >> 4) * 8;
    const int atok = mtile * 16 + fr;
    f32x4v acc[8];
    #pragma unroll
    for (int nt = 0; nt < 8; ++nt) acc[nt] = (f32x4v){0.0f, 0.0f, 0.0f, 0.0f};

    #pragma unroll
    for (int ks = 0; ks < 2; ++ks) {
        const short8v a = *(const short8v*)&hb2[(atok * 64 + ks * 32 + kb) ^ ((atok & 7) << 3)];
        #pragma unroll
        for (int nt = 0; nt < 8; ++nt) {
            const int col = nquad * 128 + nt * 16 + fr;
            const short8v bfr = *(const short8v*)&W1T[(col * 64 + ks * 32 + kb) ^ ((col & 7) << 3)];
            acc[nt] = __builtin_amdgcn_mfma_f32_16x16x32_bf16(a, bfr, acc[nt], 0, 0, 0);
        }
    }

    #pragma unroll
    for (int nt = 0; nt < 8; ++nt) {
        const int col = nquad * 128 + nt * 16 + fr;
        const float c1v = c1[col];
        #pragma unroll
        for (int r = 0; r < 4; ++r) {
            const int tok = mtile * 16 + (lane >> 4) * 4 + r;
            const float val = gelu_exact(acc[nt][r] + c1v);
            const int pk = __builtin_amdgcn_cvt_pk_fp8_f32(val, val, 0, false);
            ytile8[((unsigned)(tok * 256 + col)) ^ (((unsigned)(tok & 7)) << 4)] = (unsigned char)(pk & 0xFF);
        }
    }
    __syncthreads();

    {
        const int row = t >> 3, cb = (t & 7) * 32;
        const unsigned int swz = ((unsigned int)(row & 7)) << 4;
        unsigned char* dst = y8 + (size_t)(tok0 + row) * 256 + cb;
        #pragma unroll
        for (int j = 0; j < 2; ++j) {
            const unsigned int bidx = ((unsigned int)(row * 256 + cb + j * 16)) ^ swz;
            *(uint4*)(dst + j * 16) = *(const uint4*)&ytile8[bidx];
        }
    }
}

// ============ Kernel D: depthwise 3x3 (fp8 y) + GELU + MFMA W2 ===============
// 256 threads. LDS: zsb2 only (16 KB) -> high occupancy.
__global__ __launch_bounds__(256) void kD(
    const unsigned char* __restrict__ y8, const float* __restrict__ Wdw, const float* __restrict__ bdw,
    const unsigned short* __restrict__ w2t, const float* __restrict__ c2,
    float* __restrict__ out)
{
    __shared__ unsigned short zsb2[PIXD * 256]; // bf16 [pix][k], swizzled (16 KB)
    const int t = threadIdx.x;
    const int bid = (blockIdx.x & 7) * 256 + (blockIdx.x >> 3);
    const int b = bid >> 10;
    const int rem = bid & 1023;
    const int hh = rem >> 3;
    const int ww0 = (rem & 7) * PIXD;

    {
        const int lane = t & 63, sub = t >> 6;
        const int c4 = lane * 4;
        const int px0 = ww0 + sub * 8;
        const unsigned char* __restrict__ yb = y8 + (size_t)b * HWq * 256;
        const bool r0ok = (hh > 0), r2ok = (hh < Hq - 1);
        const int y0r = (hh - 1) << 8, y1r = hh << 8, y2r = (hh + 1) << 8;

        float um1[3][4], uz0[3][4], up1[3][4];
        #define LOADCOL(dst, xx) do {                                              \
            const unsigned int u0v = r0ok ? *(const unsigned int*)&yb[((size_t)(y0r + (xx)) << 8) + c4] : 0u; \
            const unsigned int u1v =        *(const unsigned int*)&yb[((size_t)(y1r + (xx)) << 8) + c4]; \
            const unsigned int u2v = r2ok ? *(const unsigned int*)&yb[((size_t)(y2r + (xx)) << 8) + c4] : 0u; \
            { auto lo = __builtin_amdgcn_cvt_pk_f32_fp8(u0v, false);               \
              auto hi = __builtin_amdgcn_cvt_pk_f32_fp8(u0v, true);                \
              dst[0][0] = lo[0]; dst[0][1] = lo[1]; dst[0][2] = hi[0]; dst[0][3] = hi[1]; } \
            { auto lo = __builtin_amdgcn_cvt_pk_f32_fp8(u1v, false);               \
              auto hi = __builtin_amdgcn_cvt_pk_f32_fp8(u1v, true);                \
              dst[1][0] = lo[0]; dst[1][1] = lo[1]; dst[1][2] = hi[0]; dst[1][3] = hi[1]; } \
            { auto lo = __builtin_amdgcn_cvt_pk_f32_fp8(u2v, false);               \
              auto hi = __builtin_amdgcn_cvt_pk_f32_fp8(u2v, true);                \
              dst[2][0] = lo[0]; dst[2][1] = lo[1]; dst[2][2] = hi[0]; dst[2][3] = hi[1]; } \
        } while (0)

        float wd[9][4], bdv[4];
        #pragma unroll
        for (int j = 0; j < 4; ++j) {
            bdv[j] = bdw[c4 + j];
            #pragma unroll
            for (int q = 0; q < 9; ++q) wd[q][j] = Wdw[(c4 + j) * 9 + q];
        }

        LOADCOL(um1, (px0 - 1) & 255);
        LOADCOL(uz0, px0);
        #pragma unroll
        for (int p = 0; p < 8; ++p) {
            LOADCOL(up1, (px0 + p + 1) & 255);
            unsigned short zq[4];
            #pragma unroll
            for (int j = 0; j < 4; ++j) {
                float a = bdv[j];
                #pragma unroll
                for (int ky = 0; ky < 3; ++ky) {
                    a = fmaf(wd[ky * 3 + 0][j], um1[ky][j], a);
                    a = fmaf(wd[ky * 3 + 1][j], uz0[ky][j], a);
                    a = fmaf(wd[ky * 3 + 2][j], up1[ky][j], a);
                }
                zq[j] = f2bf(gelu_exact(a));
            }
            const int pix = sub * 8 + p;
            ushort4v zv = {zq[0], zq[1], zq[2], zq[3]};
            *(ushort4v*)&zsb2[((unsigned)(pix * 256 + c4)) ^ (((unsigned)(pix & 7)) << 3)] = zv;
            #pragma unroll
            for (int ky = 0; ky < 3; ++ky)
                #pragma unroll
                for (int j = 0; j < 4; ++j) { um1[ky][j] = uz0[ky][j]; uz0[ky][j] = up1[ky][j]; }
        }
        #undef LOADCOL
    }
    __syncthreads();

    const int lane = t & 63, wv = t >> 6;
    const int fr = lane & 15;
    const int kb = (lane >> 4) * 8;
    const int col = wv * 16 + fr;
    f32x4v acc0 = {0.0f, 0.0f, 0.0f, 0.0f};
    f32x4v acc1 = {0.0f, 0.0f, 0.0f, 0.0f};
    #pragma unroll
    for (int kk = 0; kk < 8; ++kk) {
        const int ka = kk * 32 + kb;
        const short8v bfr = *(const short8v*)&w2t[(size_t)col * 256 + ka];
        const short8v a0 = *(const short8v*)&zsb2[(fr * 256 + ka) ^ ((fr & 7) << 3)];
        const short8v a1 = *(const short8v*)&zsb2[((fr + 16) * 256 + ka) ^ ((fr & 7) << 3)];
        acc0 = __builtin_amdgcn_mfma_f32_16x16x32_bf16(a0, bfr, acc0, 0, 0, 0);
        acc1 = __builtin_amdgcn_mfma_f32_16x16x32_bf16(a1, bfr, acc1, 0, 0, 0);
    }
    const float c2v = c2[col];
    #pragma unroll
    for (int r = 0; r < 4; ++r) {
        const int prow = (lane >> 4) * 4 + r;
        const size_t tok0g = (size_t)b * HWq + ((size_t)hh << 8) + ww0;
        out[(tok0g + prow) * 64 + col] += acc0[r] + c2v;
        out[(tok0g + 16 + prow) * 64 + col] += acc1[r] + c2v;
    }
}

extern "C" void kernel_launch(void* const* d_in, const int* in_sizes, int n_in,
                              void* d_out, int out_size, void* d_ws, size_t ws_size,
                              hipStream_t stream) {
    const float* x    = (const float*)d_in[0];
    const float* ref  = (const float*)d_in[1];
    const float* g1   = (const float*)d_in[2];
    const float* be1  = (const float*)d_in[3];
    const float* g2   = (const float*)d_in[4];
    const float* be2  = (const float*)d_in[5];
    const float* Woff = (const float*)d_in[6];
    const float* boff = (const float*)d_in[7];
    const float* Wa   = (const float*)d_in[8];
    const float* ba   = (const float*)d_in[9];
    const float* Wv   = (const float*)d_in[10];
    const float* bv   = (const float*)d_in[11];
    const float* Wo   = (const float*)d_in[12];
    const float* bo   = (const float*)d_in[13];
    const float* W1   = (const float*)d_in[14];
    const float* c1   = (const float*)d_in[15];
    const float* Wdw  = (const float*)d_in[16];
    const float* bdw  = (const float*)d_in[17];
    const float* W2   = (const float*)d_in[18];
    const float* c2   = (const float*)d_in[19];

    float* out = (float*)d_out;
    unsigned char* wsb = (unsigned char*)d_ws;
    unsigned char* v8 = wsb;                                        // 4 MB
    unsigned char* y8 = v8 + (size_t)Bq * 2 * HWq * 32;             // 16.8 MB
    unsigned short* w1t = (unsigned short*)(y8 + (size_t)NTOK * 256);
    unsigned short* w2t = w1t + 256 * 64;
    unsigned short* wct = w2t + 64 * 256;
    unsigned short* wot = wct + 128 * 64;

    hipLaunchKernelGGL(kPrep, dim3(88), dim3(256), 0, stream,
                       W1, W2, Wv, Woff, Wa, Wo, w1t, w2t, wct, wot);
    hipLaunchKernelGGL(kA, dim3(NTOK / TOKA), dim3(256), 0, stream,
                       x, g1, be1, wct, bv, v8);
    hipLaunchKernelGGL(kB, dim3(NTOK / TOKB), dim3(256), 0, stream,
                       x, v8, ref, wct, wot, g1, be1, boff, ba, bo, out);
    hipLaunchKernelGGL(kC, dim3(NTOK / TOKC), dim3(512), 0, stream,
                       out, g2, be2, w1t, c1, y8);
    hipLaunchKernelGGL(kD, dim3(Bq * Hq * (Wq / PIXD)), dim3(256), 0, stream,
                       y8, Wdw, bdw, w2t, c2, out);
}

// Round 21
// 87.834 us; speedup vs baseline: 1.5283x; 1.0028x over previous
//
#include <hip/hip_runtime.h>
#include <math.h>

// PanoformerBlock — locked configuration (r20): 533 -> 88 us over the session.
// Structure: kPrep (weight pack bf16-T) ; kA LN1+MFMA(Wv)->v8 fp8 ;
// kB LN1+MFMA(Woff|Wa)+softmax+fp8 16B-gather+MFMA(Wo)+residual ;
// kC LN2+MFMA(W1)+GELU->y8 fp8 ; kD depthwise3x3+GELU+MFMA(W2)+residual.
// All GEMMs on mfma_f32_16x16x32_bf16; intermediates fp8-e4m3 (HW cvt);
// XOR-swizzled LDS everywhere; XCD-chunked block swizzles for L2 locality.

#define Bq 2
#define Hq 128
#define Wq 256
#define Cq 64
#define HIDq 256
#define HWq (Hq * Wq)
#define NTOK (Bq * HWq)

#define TOKA 64
#define TOKB 64
#define TOKC 64
#define PIXD 32

typedef __attribute__((ext_vector_type(8))) short short8v;
typedef __attribute__((ext_vector_type(4))) float f32x4v;
typedef __attribute__((ext_vector_type(4))) unsigned short ushort4v;
typedef __attribute__((ext_vector_type(4))) unsigned int uint4v;

__device__ inline float gelu_exact(float x) {
    return 0.5f * x * (1.0f + erff(x * 0.70710678118654752440f));
}

__device__ inline unsigned short f2bf(float f) {
    unsigned int u = __float_as_uint(f);
    u += 0x7FFFu + ((u >> 16) & 1u);
    return (unsigned short)(u >> 16);
}

__device__ inline float bf2f(unsigned short u) {
    return __uint_as_float(((unsigned int)u) << 16);
}

// ============ Kernel P: pack weights -> bf16 transposed [col][k] in ws =======
__global__ __launch_bounds__(256) void kPrep(
    const float* __restrict__ W1, const float* __restrict__ W2,
    const float* __restrict__ Wv, const float* __restrict__ Woff, const float* __restrict__ Wa,
    const float* __restrict__ Wo,
    unsigned short* __restrict__ w1t, unsigned short* __restrict__ w2t,
    unsigned short* __restrict__ wct, unsigned short* __restrict__ wot)
{
    const int p = blockIdx.x * 256 + threadIdx.x;    // 88*256 = 22528
    if (p < 8192) {                                  // W1T: c 0..255, k2 0..31
        const int c = p >> 5, k2 = p & 31;
        const unsigned int pk = (unsigned int)f2bf(W1[(size_t)(2 * k2) * 256 + c])
                              | ((unsigned int)f2bf(W1[(size_t)(2 * k2 + 1) * 256 + c]) << 16);
        ((unsigned int*)w1t)[c * 32 + k2] = pk;
    } else if (p < 16384) {                          // W2T: c 0..63, k2 0..127
        const int q = p - 8192;
        const int c = q >> 7, k2 = q & 127;
        const unsigned int pk = (unsigned int)f2bf(W2[(size_t)(2 * k2) * 64 + c])
                              | ((unsigned int)f2bf(W2[(size_t)(2 * k2 + 1) * 64 + c]) << 16);
        ((unsigned int*)w2t)[c * 128 + k2] = pk;
    } else if (p < 20480) {                          // WcT: c 0..127, k2 0..31
        const int q = p - 16384;
        const int c = q >> 5, k2 = q & 31;
        float w0 = 0.0f, w1 = 0.0f;
        if (c < 64)       { w0 = Wv[(size_t)(2 * k2) * 64 + c];          w1 = Wv[(size_t)(2 * k2 + 1) * 64 + c]; }
        else if (c < 100) { w0 = Woff[(size_t)(2 * k2) * 36 + (c - 64)]; w1 = Woff[(size_t)(2 * k2 + 1) * 36 + (c - 64)]; }
        else if (c < 118) { w0 = Wa[(size_t)(2 * k2) * 18 + (c - 100)];  w1 = Wa[(size_t)(2 * k2 + 1) * 18 + (c - 100)]; }
        const unsigned int pk = (unsigned int)f2bf(w0) | ((unsigned int)f2bf(w1) << 16);
        ((unsigned int*)wct)[c * 32 + k2] = pk;
    } else {                                         // WoT: c 0..63, k2 0..31
        const int q = p - 20480;
        const int c = q >> 5, k2 = q & 31;
        const unsigned int pk = (unsigned int)f2bf(Wo[(size_t)(2 * k2) * 64 + c])
                              | ((unsigned int)f2bf(Wo[(size_t)(2 * k2 + 1) * 64 + c]) << 16);
        ((unsigned int*)wot)[c * 32 + k2] = pk;
    }
}

// ============ shared LN helper: thread=(tok,quarter) -> bf16 swizzled LDS ====
__device__ inline void ln_to_bf16_lds(
    const float* __restrict__ xsrc, const float* __restrict__ g, const float* __restrict__ be,
    int tok0, int t, unsigned short* __restrict__ hdst)
{
    const int tok = t >> 2, part = t & 3;
    const int chb = part * 16;
    const float* xp = xsrc + (size_t)(tok0 + tok) * 64 + chb;
    const float4 v0 = ((const float4*)xp)[0];
    const float4 v1 = ((const float4*)xp)[1];
    const float4 v2 = ((const float4*)xp)[2];
    const float4 v3 = ((const float4*)xp)[3];
    float s = ((v0.x + v0.y) + (v0.z + v0.w)) + ((v1.x + v1.y) + (v1.z + v1.w))
            + ((v2.x + v2.y) + (v2.z + v2.w)) + ((v3.x + v3.y) + (v3.z + v3.w));
    float s2 = 0.0f;
    s2 = fmaf(v0.x, v0.x, s2); s2 = fmaf(v0.y, v0.y, s2);
    s2 = fmaf(v0.z, v0.z, s2); s2 = fmaf(v0.w, v0.w, s2);
    s2 = fmaf(v1.x, v1.x, s2); s2 = fmaf(v1.y, v1.y, s2);
    s2 = fmaf(v1.z, v1.z, s2); s2 = fmaf(v1.w, v1.w, s2);
    s2 = fmaf(v2.x, v2.x, s2); s2 = fmaf(v2.y, v2.y, s2);
    s2 = fmaf(v2.z, v2.z, s2); s2 = fmaf(v2.w, v2.w, s2);
    s2 = fmaf(v3.x, v3.x, s2); s2 = fmaf(v3.y, v3.y, s2);
    s2 = fmaf(v3.z, v3.z, s2); s2 = fmaf(v3.w, v3.w, s2);
    s  += __shfl_xor(s, 1);  s2 += __shfl_xor(s2, 1);
    s  += __shfl_xor(s, 2);  s2 += __shfl_xor(s2, 2);
    const float m  = s * (1.0f / 64.0f);
    const float var = fmaf(-m, m, s2 * (1.0f / 64.0f));
    const float rs = rsqrtf(var + 1e-5f);
    const float nb = -m * rs;
    const float vv[16] = {v0.x,v0.y,v0.z,v0.w, v1.x,v1.y,v1.z,v1.w,
                          v2.x,v2.y,v2.z,v2.w, v3.x,v3.y,v3.z,v3.w};
    unsigned int pk[8];
    #pragma unroll
    for (int q = 0; q < 8; ++q) {
        const float hA = fmaf(fmaf(vv[2*q], rs, nb), g[chb + 2*q], be[chb + 2*q]);
        const float hB = fmaf(fmaf(vv[2*q+1], rs, nb), g[chb + 2*q+1], be[chb + 2*q+1]);
        pk[q] = (unsigned int)f2bf(hA) | ((unsigned int)f2bf(hB) << 16);
    }
    const unsigned int swz = ((unsigned int)(tok & 7)) << 3;
    unsigned int hi0 = ((unsigned int)(tok * 64 + chb)) ^ swz;
    unsigned int hi1 = ((unsigned int)(tok * 64 + chb + 8)) ^ swz;
    uint4 gA = {pk[0], pk[1], pk[2], pk[3]};
    uint4 gB = {pk[4], pk[5], pk[6], pk[7]};
    *(uint4*)&hdst[hi0] = gA;
    *(uint4*)&hdst[hi1] = gB;
}

// ============ Kernel A: LN1 + bf16 MFMA Wv -> v8 (fp8) =======================
// 256 threads (4 waves), 64 tokens/block.
__global__ __launch_bounds__(256) void kA(
    const float* __restrict__ x,
    const float* __restrict__ g1, const float* __restrict__ be1,
    const unsigned short* __restrict__ wct, const float* __restrict__ bv,
    unsigned char* __restrict__ v8)
{
    __shared__ unsigned short WvT[64 * 64];      // bf16 [col][k], swizzled (8 KB)
    __shared__ unsigned short hb[TOKA * 64];     // bf16 [tok][k], swizzled (8 KB)
    __shared__ unsigned char vtile[TOKA * 64];   // fp8 [tok][ch] (4 KB)
    const int t = threadIdx.x;
    const int tok0 = blockIdx.x * TOKA;
    const int b = tok0 >> 15;
    const int pix0 = tok0 & (HWq - 1);

    #pragma unroll
    for (int i = 0; i < 2; ++i) {
        const int q4 = t + i * 256;
        const uint4 d = ((const uint4*)wct)[q4];
        const int u0 = q4 * 4;
        const int c = u0 >> 5;
        const int udst = u0 ^ ((c & 7) << 2);
        *(uint4*)&((unsigned int*)WvT)[udst] = d;
    }
    ln_to_bf16_lds(x, g1, be1, tok0, t, hb);
    __syncthreads();

    const int lane = t & 63, wv = t >> 6;
    const int fr = lane & 15, kb = (lane >> 4) * 8;
    const int atok = wv * 16 + fr;
    f32x4v acc[4];
    #pragma unroll
    for (int nt = 0; nt < 4; ++nt) acc[nt] = (f32x4v){0.0f, 0.0f, 0.0f, 0.0f};
    #pragma unroll
    for (int ks = 0; ks < 2; ++ks) {
        const short8v a = *(const short8v*)&hb[(atok * 64 + ks * 32 + kb) ^ ((atok & 7) << 3)];
        #pragma unroll
        for (int nt = 0; nt < 4; ++nt) {
            const int col = nt * 16 + fr;
            const short8v bfr = *(const short8v*)&WvT[(col * 64 + ks * 32 + kb) ^ ((col & 7) << 3)];
            acc[nt] = __builtin_amdgcn_mfma_f32_16x16x32_bf16(a, bfr, acc[nt], 0, 0, 0);
        }
    }
    const int rbase = wv * 16 + (lane >> 4) * 4;
    #pragma unroll
    for (int nt = 0; nt < 4; ++nt) {
        const int col = nt * 16 + fr;
        const float bvv = bv[col];
        #pragma unroll
        for (int r = 0; r < 4; ++r) {
            const float val = acc[nt][r] + bvv;
            const int pk = __builtin_amdgcn_cvt_pk_fp8_f32(val, val, 0, false);
            vtile[(rbase + r) * 64 + col] = (unsigned char)(pk & 0xFF);
        }
    }
    __syncthreads();

    {
        const int tok = t >> 2, chunk = t & 3;
        const int n = chunk >> 1;
        const uint4 d = *(const uint4*)&vtile[tok * 64 + chunk * 16];
        *(uint4*)&v8[((size_t)(b * 2 + n) * HWq + pix0 + tok) * 32 + (chunk & 1) * 16] = d;
    }
}

// ============ Kernel B: LN1 + MFMA {Woff|Wa} + softmax + sample + MFMA Wo ====
// 256 threads (4 waves), 64 tokens/block. LDS 31744 B with region reuse:
//   lds16[0..4095]    wfa -> (after P2) woT
//   lds16[4096..8191] hb  -> (after P2) sout bf16 (hb-swizzled layout)
//   ldsf[4352,6656)   locs[64][36]
//   ldsf[6656,7936)   LG[64][20]; softmax normalizes in place
__global__ __launch_bounds__(256) void kB(
    const float* __restrict__ x, const unsigned char* __restrict__ v8,
    const float* __restrict__ ref, const unsigned short* __restrict__ wct,
    const unsigned short* __restrict__ wot,
    const float* __restrict__ g1, const float* __restrict__ be1,
    const float* __restrict__ boff, const float* __restrict__ ba,
    const float* __restrict__ bo, float* __restrict__ out)
{
    __shared__ float ldsf[7936];
    unsigned short* lds16 = (unsigned short*)ldsf;
    const int t = threadIdx.x;
    // XCD-chunked swizzle: 1024 blocks, 8 XCDs, 128 contiguous per XCD
    const int bid = (blockIdx.x & 7) * (NTOK / TOKB / 8) + (blockIdx.x >> 3);
    const int tok0 = bid * TOKB;
    const int b = tok0 >> 15;

    // ---- P1: stage wct cols 64..127 -> wfa; LN1 -> hb
    #pragma unroll
    for (int i = 0; i < 2; ++i) {
        const int q4 = t + i * 256;
        const uint4 d = ((const uint4*)wct)[q4 + 512];
        const int u0 = q4 * 4;
        const int c = u0 >> 5;
        const int udst = u0 ^ ((c & 7) << 2);
        *(uint4*)&((unsigned int*)lds16)[udst] = d;
    }
    ln_to_bf16_lds(x, g1, be1, tok0, t, lds16 + 4096);
    __syncthreads();

    // ---- P2: MFMA offsets -> locs, LG
    const int lane = t & 63, wvid = t >> 6;
    {
        const int fr = lane & 15, kb = (lane >> 4) * 8;
        const int atok = wvid * 16 + fr;
        f32x4v acc[4];
        #pragma unroll
        for (int nt = 0; nt < 4; ++nt) acc[nt] = (f32x4v){0.0f, 0.0f, 0.0f, 0.0f};
        #pragma unroll
        for (int ks = 0; ks < 2; ++ks) {
            const short8v a = *(const short8v*)&lds16[4096 + ((atok * 64 + ks * 32 + kb) ^ ((atok & 7) << 3))];
            #pragma unroll
            for (int nt = 0; nt < 4; ++nt) {
                const int col = nt * 16 + fr;
                const short8v bfr = *(const short8v*)&lds16[(col * 64 + ks * 32 + kb) ^ ((col & 7) << 3)];
                acc[nt] = __builtin_amdgcn_mfma_f32_16x16x32_bf16(a, bfr, acc[nt], 0, 0, 0);
            }
        }
        const int rbase = wvid * 16 + (lane >> 4) * 4;
        #pragma unroll
        for (int nt = 0; nt < 4; ++nt) {
            const int col = nt * 16 + fr;
            if (col < 36) {
                const int rco = (col >= 18) ? col - 18 : col;
                const float bo_ = boff[col];
                #pragma unroll
                for (int r = 0; r < 4; ++r) {
                    const size_t tokg = (size_t)tok0 + rbase + r;
                    ldsf[4352 + (rbase + r) * 36 + col] = ref[tokg * 18 + rco] + acc[nt][r] + bo_;
                }
            } else if (col < 54) {
                const int lg = col - 36;
                const float bav = ba[lg];
                #pragma unroll
                for (int r = 0; r < 4; ++r) ldsf[6656 + (rbase + r) * 20 + lg] = acc[nt][r] + bav;
            }
        }
    }
    __syncthreads();

    // ---- P3: softmax in place; stage woT into dead wfa region
    #pragma unroll
    for (int i = 0; i < 2; ++i) {
        const int q4 = t + i * 256;
        const uint4 d = ((const uint4*)wot)[q4];
        const int u0 = q4 * 4;
        const int c = u0 >> 5;
        const int udst = u0 ^ ((c & 7) << 2);
        *(uint4*)&((unsigned int*)lds16)[udst] = d;
    }
    if (t < TOKB * 2) {
        const int tk = t >> 1, head = t & 1;
        float mx = -1e30f;
        #pragma unroll
        for (int k = 0; k < 9; ++k) mx = fmaxf(mx, ldsf[6656 + tk * 20 + head * 9 + k]);
        float e[9], s = 0.0f;
        #pragma unroll
        for (int k = 0; k < 9; ++k) { e[k] = expf(ldsf[6656 + tk * 20 + head * 9 + k] - mx); s += e[k]; }
        const float inv = 1.0f / s;
        #pragma unroll
        for (int k = 0; k < 9; ++k) ldsf[6656 + tk * 20 + head * 9 + k] = e[k] * inv;
    }
    __syncthreads();

    // ---- P4: sampling -> sout bf16 (hb-swizzled) into dead hb region
    {
        const int half = lane & 1;
        const int n = (lane >> 1) & 1;
        const int tkl = wvid * 16 + (lane >> 2);
        const unsigned char* __restrict__ vimg =
            v8 + (size_t)(b * 2 + n) * HWq * 32 + half * 16;

        float a[16];
        #pragma unroll
        for (int j = 0; j < 16; ++j) a[j] = 0.0f;

        #pragma unroll
        for (int k = 0; k < 9; ++k) {
            const float2 g = *(const float2*)&ldsf[4352 + tkl * 36 + n * 18 + 2 * k];
            const float at = ldsf[6656 + tkl * 20 + n * 9 + k];
            const float ix = fmaf(g.x, 128.0f, 127.5f);
            const float iy = fmaf(g.y, 64.0f, 63.5f);
            const float x0f = floorf(ix), y0f = floorf(iy);
            const float wx1 = ix - x0f, wy1 = iy - y0f;
            const float wx0 = 1.0f - wx1, wy0 = 1.0f - wy1;
            const int x0 = (int)x0f, y0 = (int)y0f;
            const int x1i = x0 + 1, y1i = y0 + 1;
            const int x0c = min(max(x0, 0), Wq - 1), y0c = min(max(y0, 0), Hq - 1);
            const int x1c = min(max(x1i, 0), Wq - 1), y1c = min(max(y1i, 0), Hq - 1);
            const bool vx0 = (x0 >= 0) & (x0 <= Wq - 1);
            const bool vy0 = (y0 >= 0) & (y0 <= Hq - 1);
            const bool vx1 = (x1i >= 0) & (x1i <= Wq - 1);
            const bool vy1 = (y1i >= 0) & (y1i <= Hq - 1);
            const float ax0 = at * wx0, ax1 = at * wx1;
            const float w00 = (vx0 && vy0) ? ax0 * wy0 : 0.0f;
            const float w10 = (vx1 && vy0) ? ax1 * wy0 : 0.0f;
            const float w01 = (vx0 && vy1) ? ax0 * wy1 : 0.0f;
            const float w11 = (vx1 && vy1) ? ax1 * wy1 : 0.0f;
            const int p00 = (((y0c << 8) + x0c) << 5), p10 = (((y0c << 8) + x1c) << 5);
            const int p01 = (((y1c << 8) + x0c) << 5), p11 = (((y1c << 8) + x1c) << 5);
            const uint4v q00 = *(const uint4v*)(vimg + p00);
            const uint4v q10 = *(const uint4v*)(vimg + p10);
            const uint4v q01 = *(const uint4v*)(vimg + p01);
            const uint4v q11 = *(const uint4v*)(vimg + p11);
            #pragma unroll
            for (int j = 0; j < 4; ++j) {
                {
                    auto lo = __builtin_amdgcn_cvt_pk_f32_fp8(q00[j], false);
                    auto hi = __builtin_amdgcn_cvt_pk_f32_fp8(q00[j], true);
                    a[4*j+0] = fmaf(w00, lo[0], a[4*j+0]); a[4*j+1] = fmaf(w00, lo[1], a[4*j+1]);
                    a[4*j+2] = fmaf(w00, hi[0], a[4*j+2]); a[4*j+3] = fmaf(w00, hi[1], a[4*j+3]);
                }
                {
                    auto lo = __builtin_amdgcn_cvt_pk_f32_fp8(q10[j], false);
                    auto hi = __builtin_amdgcn_cvt_pk_f32_fp8(q10[j], true);
                    a[4*j+0] = fmaf(w10, lo[0], a[4*j+0]); a[4*j+1] = fmaf(w10, lo[1], a[4*j+1]);
                    a[4*j+2] = fmaf(w10, hi[0], a[4*j+2]); a[4*j+3] = fmaf(w10, hi[1], a[4*j+3]);
                }
                {
                    auto lo = __builtin_amdgcn_cvt_pk_f32_fp8(q01[j], false);
                    auto hi = __builtin_amdgcn_cvt_pk_f32_fp8(q01[j], true);
                    a[4*j+0] = fmaf(w01, lo[0], a[4*j+0]); a[4*j+1] = fmaf(w01, lo[1], a[4*j+1]);
                    a[4*j+2] = fmaf(w01, hi[0], a[4*j+2]); a[4*j+3] = fmaf(w01, hi[1], a[4*j+3]);
                }
                {
                    auto lo = __builtin_amdgcn_cvt_pk_f32_fp8(q11[j], false);
                    auto hi = __builtin_amdgcn_cvt_pk_f32_fp8(q11[j], true);
                    a[4*j+0] = fmaf(w11, lo[0], a[4*j+0]); a[4*j+1] = fmaf(w11, lo[1], a[4*j+1]);
                    a[4*j+2] = fmaf(w11, hi[0], a[4*j+2]); a[4*j+3] = fmaf(w11, hi[1], a[4*j+3]);
                }
            }
        }
        // write 16 ch as bf16 pairs in hb-swizzled layout
        const int ch0 = n * 32 + half * 16;
        unsigned int pk[8];
        #pragma unroll
        for (int q = 0; q < 8; ++q)
            pk[q] = (unsigned int)f2bf(a[2*q]) | ((unsigned int)f2bf(a[2*q+1]) << 16);
        const unsigned int swz = ((unsigned int)(tkl & 7)) << 3;
        const unsigned int hi0 = ((unsigned int)(tkl * 64 + ch0)) ^ swz;
        const unsigned int hi1 = ((unsigned int)(tkl * 64 + ch0 + 8)) ^ swz;
        uint4 gA = {pk[0], pk[1], pk[2], pk[3]};
        uint4 gB = {pk[4], pk[5], pk[6], pk[7]};
        *(uint4*)&lds16[4096 + hi0] = gA;
        *(uint4*)&lds16[4096 + hi1] = gB;
    }
    __syncthreads();

    // ---- P5: Wo MFMA (A = sout bf16, B = woT) + bias + residual -> out
    {
        const int fr = lane & 15, kb = (lane >> 4) * 8;
        const int atok = wvid * 16 + fr;
        f32x4v acc[4];
        #pragma unroll
        for (int nt = 0; nt < 4; ++nt) acc[nt] = (f32x4v){0.0f, 0.0f, 0.0f, 0.0f};
        #pragma unroll
        for (int ks = 0; ks < 2; ++ks) {
            const short8v a = *(const short8v*)&lds16[4096 + ((atok * 64 + ks * 32 + kb) ^ ((atok & 7) << 3))];
            #pragma unroll
            for (int nt = 0; nt < 4; ++nt) {
                const int col = nt * 16 + fr;
                const short8v bfr = *(const short8v*)&lds16[(col * 64 + ks * 32 + kb) ^ ((col & 7) << 3)];
                acc[nt] = __builtin_amdgcn_mfma_f32_16x16x32_bf16(a, bfr, acc[nt], 0, 0, 0);
            }
        }
        const int rbase = wvid * 16 + (lane >> 4) * 4;
        #pragma unroll
        for (int nt = 0; nt < 4; ++nt) {
            const int col = nt * 16 + fr;
            const float bov = bo[col];
            #pragma unroll
            for (int r = 0; r < 4; ++r) {
                const size_t tokg = (size_t)tok0 + rbase + r;
                out[tokg * 64 + col] = acc[nt][r] + bov + x[tokg * 64 + col];
            }
        }
    }
}

// ============ Kernel C: LN2 + bf16 MFMA W1 + GELU -> y (fp8) =================
// 512 threads (8 waves), 64 tokens/block.
__global__ __launch_bounds__(512) void kC(
    const float* __restrict__ x1, const float* __restrict__ g2, const float* __restrict__ be2,
    const unsigned short* __restrict__ w1t, const float* __restrict__ c1,
    unsigned char* __restrict__ y8)
{
    __shared__ unsigned short W1T[256 * 64];    // bf16 [col][k], swizzled (32 KB)
    __shared__ unsigned short hb2[TOKC * 64];   // bf16 [tok][k], swizzled (8 KB)
    __shared__ unsigned char ytile8[TOKC * 256];// fp8 [tok][col], swizzled (16 KB)
    const int t = threadIdx.x;
    const int tok0 = blockIdx.x * TOKC;

    #pragma unroll
    for (int i = 0; i < 4; ++i) {
        const int q4 = t + i * 512;
        const uint4 d = ((const uint4*)w1t)[q4];
        const int u0 = q4 * 4;
        const int c = u0 >> 5;
        const int udst = u0 ^ ((c & 7) << 2);
        *(uint4*)&((unsigned int*)W1T)[udst] = d;
    }
    if (t < TOKC * 4) ln_to_bf16_lds(x1, g2, be2, tok0, t, hb2);
    __syncthreads();

    const int lane = t & 63, wv = t >> 6;
    const int mtile = wv & 3, nquad = wv >> 2;
    const int fr = lane & 15, kb = (lane >> 4) * 8;
    const int atok = mtile * 16 + fr;
    f32x4v acc[8];
    #pragma unroll
    for (int nt = 0; nt < 8; ++nt) acc[nt] = (f32x4v){0.0f, 0.0f, 0.0f, 0.0f};

    #pragma unroll
    for (int ks = 0; ks < 2; ++ks) {
        const short8v a = *(const short8v*)&hb2[(atok * 64 + ks * 32 + kb) ^ ((atok & 7) << 3)];
        #pragma unroll
        for (int nt = 0; nt < 8; ++nt) {
            const int col = nquad * 128 + nt * 16 + fr;
            const short8v bfr = *(const short8v*)&W1T[(col * 64 + ks * 32 + kb) ^ ((col & 7) << 3)];
            acc[nt] = __builtin_amdgcn_mfma_f32_16x16x32_bf16(a, bfr, acc[nt], 0, 0, 0);
        }
    }

    #pragma unroll
    for (int nt = 0; nt < 8; ++nt) {
        const int col = nquad * 128 + nt * 16 + fr;
        const float c1v = c1[col];
        #pragma unroll
        for (int r = 0; r < 4; ++r) {
            const int tok = mtile * 16 + (lane >> 4) * 4 + r;
            const float val = gelu_exact(acc[nt][r] + c1v);
            const int pk = __builtin_amdgcn_cvt_pk_fp8_f32(val, val, 0, false);
            ytile8[((unsigned)(tok * 256 + col)) ^ (((unsigned)(tok & 7)) << 4)] = (unsigned char)(pk & 0xFF);
        }
    }
    __syncthreads();

    {
        const int row = t >> 3, cb = (t & 7) * 32;
        const unsigned int swz = ((unsigned int)(row & 7)) << 4;
        unsigned char* dst = y8 + (size_t)(tok0 + row) * 256 + cb;
        #pragma unroll
        for (int j = 0; j < 2; ++j) {
            const unsigned int bidx = ((unsigned int)(row * 256 + cb + j * 16)) ^ swz;
            *(uint4*)(dst + j * 16) = *(const uint4*)&ytile8[bidx];
        }
    }
}

// ============ Kernel D: depthwise 3x3 (fp8 y) + GELU + MFMA W2 ===============
// 256 threads. LDS: zsb2 only (16 KB) -> high occupancy.
__global__ __launch_bounds__(256) void kD(
    const unsigned char* __restrict__ y8, const float* __restrict__ Wdw, const float* __restrict__ bdw,
    const unsigned short* __restrict__ w2t, const float* __restrict__ c2,
    float* __restrict__ out)
{
    __shared__ unsigned short zsb2[PIXD * 256]; // bf16 [pix][k], swizzled (16 KB)
    const int t = threadIdx.x;
    const int bid = (blockIdx.x & 7) * 256 + (blockIdx.x >> 3);
    const int b = bid >> 10;
    const int rem = bid & 1023;
    const int hh = rem >> 3;
    const int ww0 = (rem & 7) * PIXD;

    {
        const int lane = t & 63, sub = t >> 6;
        const int c4 = lane * 4;
        const int px0 = ww0 + sub * 8;
        const unsigned char* __restrict__ yb = y8 + (size_t)b * HWq * 256;
        const bool r0ok = (hh > 0), r2ok = (hh < Hq - 1);
        const int y0r = (hh - 1) << 8, y1r = hh << 8, y2r = (hh + 1) << 8;

        float um1[3][4], uz0[3][4], up1[3][4];
        #define LOADCOL(dst, xx) do {                                              \
            const unsigned int u0v = r0ok ? *(const unsigned int*)&yb[((size_t)(y0r + (xx)) << 8) + c4] : 0u; \
            const unsigned int u1v =        *(const unsigned int*)&yb[((size_t)(y1r + (xx)) << 8) + c4]; \
            const unsigned int u2v = r2ok ? *(const unsigned int*)&yb[((size_t)(y2r + (xx)) << 8) + c4] : 0u; \
            { auto lo = __builtin_amdgcn_cvt_pk_f32_fp8(u0v, false);               \
              auto hi = __builtin_amdgcn_cvt_pk_f32_fp8(u0v, true);                \
              dst[0][0] = lo[0]; dst[0][1] = lo[1]; dst[0][2] = hi[0]; dst[0][3] = hi[1]; } \
            { auto lo = __builtin_amdgcn_cvt_pk_f32_fp8(u1v, false);               \
              auto hi = __builtin_amdgcn_cvt_pk_f32_fp8(u1v, true);                \
              dst[1][0] = lo[0]; dst[1][1] = lo[1]; dst[1][2] = hi[0]; dst[1][3] = hi[1]; } \
            { auto lo = __builtin_amdgcn_cvt_pk_f32_fp8(u2v, false);               \
              auto hi = __builtin_amdgcn_cvt_pk_f32_fp8(u2v, true);                \
              dst[2][0] = lo[0]; dst[2][1] = lo[1]; dst[2][2] = hi[0]; dst[2][3] = hi[1]; } \
        } while (0)

        float wd[9][4], bdv[4];
        #pragma unroll
        for (int j = 0; j < 4; ++j) {
            bdv[j] = bdw[c4 + j];
            #pragma unroll
            for (int q = 0; q < 9; ++q) wd[q][j] = Wdw[(c4 + j) * 9 + q];
        }

        LOADCOL(um1, (px0 - 1) & 255);
        LOADCOL(uz0, px0);
        #pragma unroll
        for (int p = 0; p < 8; ++p) {
            LOADCOL(up1, (px0 + p + 1) & 255);
            unsigned short zq[4];
            #pragma unroll
            for (int j = 0; j < 4; ++j) {
                float a = bdv[j];
                #pragma unroll
                for (int ky = 0; ky < 3; ++ky) {
                    a = fmaf(wd[ky * 3 + 0][j], um1[ky][j], a);
                    a = fmaf(wd[ky * 3 + 1][j], uz0[ky][j], a);
                    a = fmaf(wd[ky * 3 + 2][j], up1[ky][j], a);
                }
                zq[j] = f2bf(gelu_exact(a));
            }
            const int pix = sub * 8 + p;
            ushort4v zv = {zq[0], zq[1], zq[2], zq[3]};
            *(ushort4v*)&zsb2[((unsigned)(pix * 256 + c4)) ^ (((unsigned)(pix & 7)) << 3)] = zv;
            #pragma unroll
            for (int ky = 0; ky < 3; ++ky)
                #pragma unroll
                for (int j = 0; j < 4; ++j) { um1[ky][j] = uz0[ky][j]; uz0[ky][j] = up1[ky][j]; }
        }
        #undef LOADCOL
    }
    __syncthreads();

    const int lane = t & 63, wv = t >> 6;
    const int fr = lane & 15;
    const int kb = (lane >> 4) * 8;
    const int col = wv * 16 + fr;
    f32x4v acc0 = {0.0f, 0.0f, 0.0f, 0.0f};
    f32x4v acc1 = {0.0f, 0.0f, 0.0f, 0.0f};
    #pragma unroll
    for (int kk = 0; kk < 8; ++kk) {
        const int ka = kk * 32 + kb;
        const short8v bfr = *(const short8v*)&w2t[(size_t)col * 256 + ka];
        const short8v a0 = *(const short8v*)&zsb2[(fr * 256 + ka) ^ ((fr & 7) << 3)];
        const short8v a1 = *(const short8v*)&zsb2[((fr + 16) * 256 + ka) ^ ((fr & 7) << 3)];
        acc0 = __builtin_amdgcn_mfma_f32_16x16x32_bf16(a0, bfr, acc0, 0, 0, 0);
        acc1 = __builtin_amdgcn_mfma_f32_16x16x32_bf16(a1, bfr, acc1, 0, 0, 0);
    }
    const float c2v = c2[col];
    #pragma unroll
    for (int r = 0; r < 4; ++r) {
        const int prow = (lane >> 4) * 4 + r;
        const size_t tok0g = (size_t)b * HWq + ((size_t)hh << 8) + ww0;
        out[(tok0g + prow) * 64 + col] += acc0[r] + c2v;
        out[(tok0g + 16 + prow) * 64 + col] += acc1[r] + c2v;
    }
}

extern "C" void kernel_launch(void* const* d_in, const int* in_sizes, int n_in,
                              void* d_out, int out_size, void* d_ws, size_t ws_size,
                              hipStream_t stream) {
    const float* x    = (const float*)d_in[0];
    const float* ref  = (const float*)d_in[1];
    const float* g1   = (const float*)d_in[2];
    const float* be1  = (const float*)d_in[3];
    const float* g2   = (const float*)d_in[4];
    const float* be2  = (const float*)d_in[5];
    const float* Woff = (const float*)d_in[6];
    const float* boff = (const float*)d_in[7];
    const float* Wa   = (const float*)d_in[8];
    const float* ba   = (const float*)d_in[9];
    const float* Wv   = (const float*)d_in[10];
    const float* bv   = (const float*)d_in[11];
    const float* Wo   = (const float*)d_in[12];
    const float* bo   = (const float*)d_in[13];
    const float* W1   = (const float*)d_in[14];
    const float* c1   = (const float*)d_in[15];
    const float* Wdw  = (const float*)d_in[16];
    const float* bdw  = (const float*)d_in[17];
    const float* W2   = (const float*)d_in[18];
    const float* c2   = (const float*)d_in[19];

    float* out = (float*)d_out;
    unsigned char* wsb = (unsigned char*)d_ws;
    unsigned char* v8 = wsb;                                        // 4 MB
    unsigned char* y8 = v8 + (size_t)Bq * 2 * HWq * 32;             // 16.8 MB
    unsigned short* w1t = (unsigned short*)(y8 + (size_t)NTOK * 256);
    unsigned short* w2t = w1t + 256 * 64;
    unsigned short* wct = w2t + 64 * 256;
    unsigned short* wot = wct + 128 * 64;

    hipLaunchKernelGGL(kPrep, dim3(88), dim3(256), 0, stream,
                       W1, W2, Wv, Woff, Wa, Wo, w1t, w2t, wct, wot);
    hipLaunchKernelGGL(kA, dim3(NTOK / TOKA), dim3(256), 0, stream,
                       x, g1, be1, wct, bv, v8);
    hipLaunchKernelGGL(kB, dim3(NTOK / TOKB), dim3(256), 0, stream,
                       x, v8, ref, wct, wot, g1, be1, boff, ba, bo, out);
    hipLaunchKernelGGL(kC, dim3(NTOK / TOKC), dim3(512), 0, stream,
                       out, g2, be2, w1t, c1, y8);
    hipLaunchKernelGGL(kD, dim3(Bq * Hq * (Wq / PIXD)), dim3(256), 0, stream,
                       y8, Wdw, bdw, w2t, c2, out);
}